// Round 3
// baseline (471.509 us; speedup 1.0000x reference)
//
#include <hip/hip_runtime.h>

// MHSA: X(1,2048,2048) fp32; W_Q/K/V(16,2048,128); W_out(2048,2048); out (2048,2048) fp32.
// R3: attn redesigned — K/V fragments loaded DIRECTLY from L2-resident global (XCD swizzle
// pins 2 heads/XCD), no K/V LDS staging, no barriers in main loop (P transpose LDS is
// per-wave). R2's reg-prefetch spilled to scratch (WRITE_SIZE 180MB) — removed.
// Workspace layout (needs 64 MiB): see round 0 comment (unchanged).

typedef unsigned short u16;
typedef __bf16 bf16x8 __attribute__((ext_vector_type(8)));
typedef float f32x4 __attribute__((ext_vector_type(4)));
typedef __attribute__((address_space(1))) void gvoid;
typedef __attribute__((address_space(3))) void svoid;

union B8 { uint4 u; uint2 d[2]; bf16x8 b; };

__device__ __forceinline__ u16 f2b(float f) {
  unsigned int u = __float_as_uint(f);
  unsigned int r = (u + 0x7FFFu + ((u >> 16) & 1u)) >> 16;  // RNE
  return (u16)r;
}

// ---------------- convert X: fp32 -> bf16, 4 elems/thread ----------------
__global__ __launch_bounds__(256) void cvt_x_kernel(const float* __restrict__ x,
                                                    u16* __restrict__ xb) {
  int i = (blockIdx.x * 256 + threadIdx.x) * 4;
  float4 v = *(const float4*)(x + i);
  ushort4 o;
  o.x = f2b(v.x); o.y = f2b(v.y); o.z = f2b(v.z); o.w = f2b(v.w);
  *(ushort4*)(xb + i) = o;
}

// ------- transpose+convert: src (batch,K,N) f32 -> dst (batch,N,K) bf16 -------
__global__ __launch_bounds__(256) void tcvt_kernel(const float* __restrict__ src,
                                                   u16* __restrict__ dst, int K, int N) {
  __shared__ float t[32][33];
  int bz = blockIdx.z;
  int n0 = blockIdx.x * 32, k0 = blockIdx.y * 32;
  const float* S = src + (size_t)bz * K * N;
  u16* D = dst + (size_t)bz * K * N;
  int tx = threadIdx.x, ty = threadIdx.y;  // (32,8)
#pragma unroll
  for (int d = 0; d < 4; ++d)
    t[ty + d * 8][tx] = S[(size_t)(k0 + ty + d * 8) * N + n0 + tx];
  __syncthreads();
#pragma unroll
  for (int d = 0; d < 4; ++d)
    D[(size_t)(n0 + ty + d * 8) * K + k0 + tx] = f2b(t[tx][ty + d * 8]);
}

// ---------------- shared GEMM mainloop: C(128x128) = A(128x2048) * B^T(128x2048)^T --------
// LDS tiles [128][64] bf16, XOR-swizzled (byte ^= ((byte>>7)&7)<<4); global_load_lds
// writes linearly -> source addresses pre-inverse-swizzled (m173/m201 pattern).
__device__ __forceinline__ void gemm_mainloop(const u16* Ag, const u16* Bg,
                                              u16* As, u16* Bs,
                                              f32x4 acc[4][4], int tid) {
  const int lane = tid & 63;
  const int wr = tid >> 7, wc = (tid >> 6) & 1;  // 4 waves in 2x2, wave tile 64x64
  for (int k0 = 0; k0 < 2048; k0 += 64) {
    __syncthreads();  // previous iter's reads done before overwrite
#pragma unroll
    for (int it = 0; it < 4; ++it) {
      int s = it * 256 + tid;
      int pb = s * 16;                           // physical (linear) LDS byte
      int lb = pb ^ ((((pb) >> 7) & 7) << 4);    // logical byte (involution)
      int row = lb >> 7;                         // 0..127
      int k8 = (lb >> 4) & 7;                    // 16B granule within row
      const u16* ga = Ag + (size_t)row * 2048 + k0 + k8 * 8;
      const u16* gb = Bg + (size_t)row * 2048 + k0 + k8 * 8;
      char* la = (char*)As + it * 4096 + (tid & 192) * 16;  // wave-uniform base
      char* lb2 = (char*)Bs + it * 4096 + (tid & 192) * 16;
      __builtin_amdgcn_global_load_lds((gvoid*)(void*)ga, (svoid*)la, 16, 0, 0);
      __builtin_amdgcn_global_load_lds((gvoid*)(void*)gb, (svoid*)lb2, 16, 0, 0);
    }
    __syncthreads();
#pragma unroll
    for (int ks = 0; ks < 2; ++ks) {
      B8 a[4], b[4];
#pragma unroll
      for (int i = 0; i < 4; ++i) {
        int rowa = wr * 64 + i * 16 + (lane & 15);
        int ba = rowa * 128 + ks * 64 + (lane >> 4) * 16;
        ba ^= (rowa & 7) << 4;
        a[i].u = *(const uint4*)((const char*)As + ba);
        int rowb = wc * 64 + i * 16 + (lane & 15);
        int bb = rowb * 128 + ks * 64 + (lane >> 4) * 16;
        bb ^= (rowb & 7) << 4;
        b[i].u = *(const uint4*)((const char*)Bs + bb);
      }
      __builtin_amdgcn_s_setprio(1);
#pragma unroll
      for (int i = 0; i < 4; ++i)
#pragma unroll
        for (int j = 0; j < 4; ++j)
          acc[i][j] = __builtin_amdgcn_mfma_f32_16x16x32_bf16(a[i].b, b[j].b, acc[i][j], 0, 0, 0);
      __builtin_amdgcn_s_setprio(0);
    }
  }
}

// ---------------- fused QKV projection ----------------
// 1D grid 768 blocks; XCD swizzle: each XCD gets 6 col-tiles x all 16 m-tiles.
__global__ __launch_bounds__(256) void qkv_gemm_kernel(const u16* __restrict__ Xb,
                                                       const u16* __restrict__ Wb,
                                                       u16* __restrict__ Qb,
                                                       u16* __restrict__ Kb,
                                                       u16* __restrict__ VTb) {
  __shared__ __align__(16) u16 As[128 * 64];
  __shared__ __align__(16) u16 Bs[128 * 64];
  int tid = threadIdx.x;
  int o = blockIdx.x;
  int swz = (o & 7) * 96 + (o >> 3);
  int m0 = (swz & 15) * 128;
  int c0 = swz >> 4;             // 0..47
  int tau = c0 >> 4, head = c0 & 15;
  f32x4 z = {0.f, 0.f, 0.f, 0.f};
  f32x4 acc[4][4];
#pragma unroll
  for (int i = 0; i < 4; ++i)
#pragma unroll
    for (int j = 0; j < 4; ++j) acc[i][j] = z;
  gemm_mainloop(Xb + (size_t)m0 * 2048, Wb + (size_t)c0 * 128 * 2048, As, Bs, acc, tid);

  int lane = tid & 63, wr = tid >> 7, wc = (tid >> 6) & 1;
  if (tau < 2) {
    u16* Oh = ((tau == 0) ? Qb : Kb) + (size_t)head * 2048 * 128;
    float sc = (tau == 0) ? 0.08838834764831845f : 1.0f;  // fold 1/sqrt(128) into Q
#pragma unroll
    for (int i = 0; i < 4; ++i) {
      int rb = m0 + wr * 64 + i * 16 + (lane >> 4) * 4;  // C layout: row=(l>>4)*4+r
#pragma unroll
      for (int j = 0; j < 4; ++j) {
        int col = wc * 64 + j * 16 + (lane & 15);        // C layout: col=l&15
#pragma unroll
        for (int r = 0; r < 4; ++r)
          Oh[(size_t)(rb + r) * 128 + col] = f2b(acc[i][j][r] * sc);
      }
    }
  } else {  // V: store transposed (h, t) so PV B-operand is k-contiguous
    u16* Vh = VTb + (size_t)head * 128 * 2048;
#pragma unroll
    for (int i = 0; i < 4; ++i) {
      int rb = m0 + wr * 64 + i * 16 + (lane >> 4) * 4;
#pragma unroll
      for (int j = 0; j < 4; ++j) {
        int col = wc * 64 + j * 16 + (lane & 15);
        ushort4 v;
        v.x = f2b(acc[i][j][0]); v.y = f2b(acc[i][j][1]);
        v.z = f2b(acc[i][j][2]); v.w = f2b(acc[i][j][3]);
        *(ushort4*)(Vh + (size_t)col * 2048 + rb) = v;   // 4 consecutive t -> 8B store
      }
    }
  }
}

// ---------------- flash attention (direct-from-L2 fragments, barrier-free) ----------------
// 1D grid 512; swz=(bid&7)*64+(bid>>3): XCD x owns heads {2x,2x+1} -> KV (2MB) L2-resident.
// 4 waves x 16 q-rows, KV tile 64. K/V MFMA fragments loaded straight from global (L2/L1);
// only P goes through LDS (per-wave transpose, stride 68 u16) -> NO __syncthreads in loop.
__global__ __launch_bounds__(256) void attn_kernel(const u16* __restrict__ Qb,
                                                   const u16* __restrict__ Kb,
                                                   const u16* __restrict__ VTb,
                                                   u16* __restrict__ Rb) {
  __shared__ __align__(16) u16 Ps[4 * 16 * 68];
  int tid = threadIdx.x, lane = tid & 63, w = tid >> 6;
  int bid = blockIdx.x;
  int swz = (bid & 7) * 64 + (bid >> 3);
  int head = swz >> 5;
  int q0 = (swz & 31) * 64;
  const u16* Qh = Qb + (size_t)head * 2048 * 128;
  const u16* Kh = Kb + (size_t)head * 2048 * 128;
  const u16* Vh = VTb + (size_t)head * 128 * 2048;

  // Q fragments in registers for whole kernel (A layout: row=l&15, k contig)
  B8 q[4];
  {
    int qrow = q0 + w * 16 + (lane & 15);
#pragma unroll
    for (int ks = 0; ks < 4; ++ks)
      q[ks].u = *(const uint4*)(Qh + (size_t)qrow * 128 + ks * 32 + (lane >> 4) * 8);
  }

  f32x4 o[8];
  f32x4 z4 = {0.f, 0.f, 0.f, 0.f};
#pragma unroll
  for (int f = 0; f < 8; ++f) o[f] = z4;
  float m_run[4] = {-1e30f, -1e30f, -1e30f, -1e30f};
  float l_run[4] = {0.f, 0.f, 0.f, 0.f};

  // per-lane fixed offsets
  const int kfrow = lane & 15;              // fragment row within 16
  const int kcol8 = (lane >> 4) * 8;        // k-offset within 32-slice
  u16* Pw = Ps + w * 16 * 68;

  for (int it = 0; it < 32; ++it) {
    int s0 = it * 64;

    // ---- S = Q K^T (Q pre-scaled); K frags direct from global (L2-resident) ----
    f32x4 s[4];
#pragma unroll
    for (int f = 0; f < 4; ++f) s[f] = z4;
#pragma unroll
    for (int f = 0; f < 4; ++f) {
      const u16* krow = Kh + (size_t)(s0 + f * 16 + kfrow) * 128 + kcol8;
      B8 kb0, kb1, kb2, kb3;
      kb0.u = *(const uint4*)(krow);
      kb1.u = *(const uint4*)(krow + 32);
      kb2.u = *(const uint4*)(krow + 64);
      kb3.u = *(const uint4*)(krow + 96);
      __builtin_amdgcn_s_setprio(1);
      s[f] = __builtin_amdgcn_mfma_f32_16x16x32_bf16(q[0].b, kb0.b, s[f], 0, 0, 0);
      s[f] = __builtin_amdgcn_mfma_f32_16x16x32_bf16(q[1].b, kb1.b, s[f], 0, 0, 0);
      s[f] = __builtin_amdgcn_mfma_f32_16x16x32_bf16(q[2].b, kb2.b, s[f], 0, 0, 0);
      s[f] = __builtin_amdgcn_mfma_f32_16x16x32_bf16(q[3].b, kb3.b, s[f], 0, 0, 0);
      __builtin_amdgcn_s_setprio(0);
    }

    // ---- online softmax; lane's rows = (l>>4)*4+i, cols = f*16 + (l&15) ----
    float mt[4];
#pragma unroll
    for (int i = 0; i < 4; ++i)
      mt[i] = fmaxf(fmaxf(s[0][i], s[1][i]), fmaxf(s[2][i], s[3][i]));
#pragma unroll
    for (int mask = 1; mask <= 8; mask <<= 1)
#pragma unroll
      for (int i = 0; i < 4; ++i) mt[i] = fmaxf(mt[i], __shfl_xor(mt[i], mask, 64));

    float al[4];
#pragma unroll
    for (int i = 0; i < 4; ++i) {
      float mn = fmaxf(m_run[i], mt[i]);
      al[i] = __expf(m_run[i] - mn);
      m_run[i] = mn;
    }
    float ps[4] = {0.f, 0.f, 0.f, 0.f};
#pragma unroll
    for (int f = 0; f < 4; ++f)
#pragma unroll
      for (int i = 0; i < 4; ++i) {
        float p = __expf(s[f][i] - m_run[i]);
        ps[i] += p;
        Pw[((lane >> 4) * 4 + i) * 68 + f * 16 + (lane & 15)] = f2b(p);
      }
#pragma unroll
    for (int mask = 1; mask <= 8; mask <<= 1)
#pragma unroll
      for (int i = 0; i < 4; ++i) ps[i] += __shfl_xor(ps[i], mask, 64);
#pragma unroll
    for (int i = 0; i < 4; ++i) l_run[i] = l_run[i] * al[i] + ps[i];

    // ---- rescale O; read P as A-frags (same-wave LDS dep, compiler waits) ----
#pragma unroll
    for (int f = 0; f < 8; ++f)
#pragma unroll
      for (int i = 0; i < 4; ++i) o[f][i] *= al[i];

    B8 pa[2];
#pragma unroll
    for (int k2 = 0; k2 < 2; ++k2) {
      const u16* pp = Pw + (lane & 15) * 68 + k2 * 32 + (lane >> 4) * 8;
      pa[k2].d[0] = *(const uint2*)(pp);
      pa[k2].d[1] = *(const uint2*)(pp + 4);
    }

    // ---- O += P*V; V^T frags direct from global (L2-resident) ----
#pragma unroll
    for (int f = 0; f < 8; ++f) {
      const u16* vrow = Vh + (size_t)(f * 16 + kfrow) * 2048 + s0 + kcol8;
      B8 vb0, vb1;
      vb0.u = *(const uint4*)(vrow);
      vb1.u = *(const uint4*)(vrow + 32);
      __builtin_amdgcn_s_setprio(1);
      o[f] = __builtin_amdgcn_mfma_f32_16x16x32_bf16(pa[0].b, vb0.b, o[f], 0, 0, 0);
      o[f] = __builtin_amdgcn_mfma_f32_16x16x32_bf16(pa[1].b, vb1.b, o[f], 0, 0, 0);
      __builtin_amdgcn_s_setprio(0);
    }
  }

  // normalize and write R in (t, n*128+h) layout
#pragma unroll
  for (int i = 0; i < 4; ++i) {
    float inv = 1.0f / l_run[i];
    int row = q0 + w * 16 + (lane >> 4) * 4 + i;
#pragma unroll
    for (int f = 0; f < 8; ++f) {
      int col = head * 128 + f * 16 + (lane & 15);
      Rb[(size_t)row * 2048 + col] = f2b(o[f][i] * inv);
    }
  }
}

// ---------------- output projection: out = R(2048x2048) * W_out ----------------
__global__ __launch_bounds__(256) void out_gemm_kernel(const u16* __restrict__ Rb,
                                                       const u16* __restrict__ Wob,
                                                       float* __restrict__ out) {
  __shared__ __align__(16) u16 As[128 * 64];
  __shared__ __align__(16) u16 Bs[128 * 64];
  int tid = threadIdx.x;
  int o = blockIdx.x;
  int swz = (o & 7) * 32 + (o >> 3);
  int m0 = (swz & 15) * 128, n0 = (swz >> 4) * 128;
  f32x4 z = {0.f, 0.f, 0.f, 0.f};
  f32x4 acc[4][4];
#pragma unroll
  for (int i = 0; i < 4; ++i)
#pragma unroll
    for (int j = 0; j < 4; ++j) acc[i][j] = z;
  gemm_mainloop(Rb + (size_t)m0 * 2048, Wob + (size_t)n0 * 2048, As, Bs, acc, tid);

  int lane = tid & 63, wr = tid >> 7, wc = (tid >> 6) & 1;
#pragma unroll
  for (int i = 0; i < 4; ++i) {
    int rb = m0 + wr * 64 + i * 16 + (lane >> 4) * 4;
#pragma unroll
    for (int j = 0; j < 4; ++j) {
      int col = n0 + wc * 64 + j * 16 + (lane & 15);
#pragma unroll
      for (int r = 0; r < 4; ++r)
        out[(size_t)(rb + r) * 2048 + col] = acc[i][j][r];
    }
  }
}

extern "C" void kernel_launch(void* const* d_in, const int* in_sizes, int n_in,
                              void* d_out, int out_size, void* d_ws, size_t ws_size,
                              hipStream_t stream) {
  const float* X  = (const float*)d_in[0];
  const float* WQ = (const float*)d_in[1];
  const float* WK = (const float*)d_in[2];
  const float* WV = (const float*)d_in[3];
  const float* WO = (const float*)d_in[4];
  float* out = (float*)d_out;

  char* ws = (char*)d_ws;
  const size_t MB8 = 8u << 20;
  u16* Xb    = (u16*)(ws);
  u16* Wqkvb = (u16*)(ws + MB8);          // 3 x 8 MiB
  u16* Woutb = (u16*)(ws + 4 * MB8);
  u16* Qb    = (u16*)(ws + 5 * MB8);
  u16* Kb    = (u16*)(ws + 6 * MB8);
  u16* VTb   = (u16*)(ws + 7 * MB8);
  u16* Rbuf  = (u16*)(ws + MB8);          // aliases Wqkvb[W_Q]: dead after qkv_gemm

  cvt_x_kernel<<<dim3(4096), dim3(256), 0, stream>>>(X, Xb);
  tcvt_kernel<<<dim3(4, 64, 16), dim3(32, 8), 0, stream>>>(WQ, Wqkvb, 2048, 128);
  tcvt_kernel<<<dim3(4, 64, 16), dim3(32, 8), 0, stream>>>(WK, Wqkvb + (size_t)16 * 128 * 2048, 2048, 128);
  tcvt_kernel<<<dim3(4, 64, 16), dim3(32, 8), 0, stream>>>(WV, Wqkvb + (size_t)32 * 128 * 2048, 2048, 128);
  tcvt_kernel<<<dim3(64, 64, 1), dim3(32, 8), 0, stream>>>(WO, Woutb, 2048, 2048);

  qkv_gemm_kernel<<<dim3(768), dim3(256), 0, stream>>>(Xb, Wqkvb, Qb, Kb, VTb);
  attn_kernel<<<dim3(512), dim3(256), 0, stream>>>(Qb, Kb, VTb, Rbuf);
  out_gemm_kernel<<<dim3(256), dim3(256), 0, stream>>>(Rbuf, Woutb, out);
}

// Round 4
// 395.288 us; speedup vs baseline: 1.1928x; 1.1928x over previous
//
#include <hip/hip_runtime.h>

// MHSA: X(1,2048,2048) fp32; W_Q/K/V(16,2048,128); W_out(2048,2048); out (2048,2048) fp32.
// R4: attn = R2 structure (LDS-staged K/V, T14 reg-prefetch write-late, XCD swizzle pinning
// 2 heads/XCD so KV is L2-resident) + __launch_bounds__(256,2) so the 32-VGPR prefetch
// fits in registers instead of spilling to scratch (R2: VGPR capped at 76, 180MB scratch
// writes). V-prefetch issued after QK^T to shorten live range. R3 (direct-from-L2 frags)
// proved FETCH=essential but was latency-serialized (MfmaUtil 5.7%) — reverted.
// Workspace layout (needs 64 MiB): see round 0 comment (unchanged).

typedef unsigned short u16;
typedef __bf16 bf16x8 __attribute__((ext_vector_type(8)));
typedef float f32x4 __attribute__((ext_vector_type(4)));
typedef __attribute__((address_space(1))) void gvoid;
typedef __attribute__((address_space(3))) void svoid;

union B8 { uint4 u; uint2 d[2]; bf16x8 b; };

__device__ __forceinline__ u16 f2b(float f) {
  unsigned int u = __float_as_uint(f);
  unsigned int r = (u + 0x7FFFu + ((u >> 16) & 1u)) >> 16;  // RNE
  return (u16)r;
}

// ---------------- convert X: fp32 -> bf16, 4 elems/thread ----------------
__global__ __launch_bounds__(256) void cvt_x_kernel(const float* __restrict__ x,
                                                    u16* __restrict__ xb) {
  int i = (blockIdx.x * 256 + threadIdx.x) * 4;
  float4 v = *(const float4*)(x + i);
  ushort4 o;
  o.x = f2b(v.x); o.y = f2b(v.y); o.z = f2b(v.z); o.w = f2b(v.w);
  *(ushort4*)(xb + i) = o;
}

// ------- transpose+convert: src (batch,K,N) f32 -> dst (batch,N,K) bf16 -------
__global__ __launch_bounds__(256) void tcvt_kernel(const float* __restrict__ src,
                                                   u16* __restrict__ dst, int K, int N) {
  __shared__ float t[32][33];
  int bz = blockIdx.z;
  int n0 = blockIdx.x * 32, k0 = blockIdx.y * 32;
  const float* S = src + (size_t)bz * K * N;
  u16* D = dst + (size_t)bz * K * N;
  int tx = threadIdx.x, ty = threadIdx.y;  // (32,8)
#pragma unroll
  for (int d = 0; d < 4; ++d)
    t[ty + d * 8][tx] = S[(size_t)(k0 + ty + d * 8) * N + n0 + tx];
  __syncthreads();
#pragma unroll
  for (int d = 0; d < 4; ++d)
    D[(size_t)(n0 + ty + d * 8) * K + k0 + tx] = f2b(t[tx][ty + d * 8]);
}

// ---------------- shared GEMM mainloop: C(128x128) = A(128x2048) * B^T(128x2048)^T --------
// LDS tiles [128][64] bf16, XOR-swizzled (byte ^= ((byte>>7)&7)<<4); global_load_lds
// writes linearly -> source addresses pre-inverse-swizzled (m173/m201 pattern).
__device__ __forceinline__ void gemm_mainloop(const u16* Ag, const u16* Bg,
                                              u16* As, u16* Bs,
                                              f32x4 acc[4][4], int tid) {
  const int lane = tid & 63;
  const int wr = tid >> 7, wc = (tid >> 6) & 1;  // 4 waves in 2x2, wave tile 64x64
  for (int k0 = 0; k0 < 2048; k0 += 64) {
    __syncthreads();  // previous iter's reads done before overwrite
#pragma unroll
    for (int it = 0; it < 4; ++it) {
      int s = it * 256 + tid;
      int pb = s * 16;                           // physical (linear) LDS byte
      int lb = pb ^ ((((pb) >> 7) & 7) << 4);    // logical byte (involution)
      int row = lb >> 7;                         // 0..127
      int k8 = (lb >> 4) & 7;                    // 16B granule within row
      const u16* ga = Ag + (size_t)row * 2048 + k0 + k8 * 8;
      const u16* gb = Bg + (size_t)row * 2048 + k0 + k8 * 8;
      char* la = (char*)As + it * 4096 + (tid & 192) * 16;  // wave-uniform base
      char* lb2 = (char*)Bs + it * 4096 + (tid & 192) * 16;
      __builtin_amdgcn_global_load_lds((gvoid*)(void*)ga, (svoid*)la, 16, 0, 0);
      __builtin_amdgcn_global_load_lds((gvoid*)(void*)gb, (svoid*)lb2, 16, 0, 0);
    }
    __syncthreads();
#pragma unroll
    for (int ks = 0; ks < 2; ++ks) {
      B8 a[4], b[4];
#pragma unroll
      for (int i = 0; i < 4; ++i) {
        int rowa = wr * 64 + i * 16 + (lane & 15);
        int ba = rowa * 128 + ks * 64 + (lane >> 4) * 16;
        ba ^= (rowa & 7) << 4;
        a[i].u = *(const uint4*)((const char*)As + ba);
        int rowb = wc * 64 + i * 16 + (lane & 15);
        int bb = rowb * 128 + ks * 64 + (lane >> 4) * 16;
        bb ^= (rowb & 7) << 4;
        b[i].u = *(const uint4*)((const char*)Bs + bb);
      }
      __builtin_amdgcn_s_setprio(1);
#pragma unroll
      for (int i = 0; i < 4; ++i)
#pragma unroll
        for (int j = 0; j < 4; ++j)
          acc[i][j] = __builtin_amdgcn_mfma_f32_16x16x32_bf16(a[i].b, b[j].b, acc[i][j], 0, 0, 0);
      __builtin_amdgcn_s_setprio(0);
    }
  }
}

// ---------------- fused QKV projection ----------------
// 1D grid 768 blocks; XCD swizzle: each XCD gets 6 col-tiles x all 16 m-tiles.
__global__ __launch_bounds__(256) void qkv_gemm_kernel(const u16* __restrict__ Xb,
                                                       const u16* __restrict__ Wb,
                                                       u16* __restrict__ Qb,
                                                       u16* __restrict__ Kb,
                                                       u16* __restrict__ VTb) {
  __shared__ __align__(16) u16 As[128 * 64];
  __shared__ __align__(16) u16 Bs[128 * 64];
  int tid = threadIdx.x;
  int o = blockIdx.x;
  int swz = (o & 7) * 96 + (o >> 3);
  int m0 = (swz & 15) * 128;
  int c0 = swz >> 4;             // 0..47
  int tau = c0 >> 4, head = c0 & 15;
  f32x4 z = {0.f, 0.f, 0.f, 0.f};
  f32x4 acc[4][4];
#pragma unroll
  for (int i = 0; i < 4; ++i)
#pragma unroll
    for (int j = 0; j < 4; ++j) acc[i][j] = z;
  gemm_mainloop(Xb + (size_t)m0 * 2048, Wb + (size_t)c0 * 128 * 2048, As, Bs, acc, tid);

  int lane = tid & 63, wr = tid >> 7, wc = (tid >> 6) & 1;
  if (tau < 2) {
    u16* Oh = ((tau == 0) ? Qb : Kb) + (size_t)head * 2048 * 128;
    float sc = (tau == 0) ? 0.08838834764831845f : 1.0f;  // fold 1/sqrt(128) into Q
#pragma unroll
    for (int i = 0; i < 4; ++i) {
      int rb = m0 + wr * 64 + i * 16 + (lane >> 4) * 4;  // C layout: row=(l>>4)*4+r
#pragma unroll
      for (int j = 0; j < 4; ++j) {
        int col = wc * 64 + j * 16 + (lane & 15);        // C layout: col=l&15
#pragma unroll
        for (int r = 0; r < 4; ++r)
          Oh[(size_t)(rb + r) * 128 + col] = f2b(acc[i][j][r] * sc);
      }
    }
  } else {  // V: store transposed (h, t) so PV B-operand is k-contiguous
    u16* Vh = VTb + (size_t)head * 128 * 2048;
#pragma unroll
    for (int i = 0; i < 4; ++i) {
      int rb = m0 + wr * 64 + i * 16 + (lane >> 4) * 4;
#pragma unroll
      for (int j = 0; j < 4; ++j) {
        int col = wc * 64 + j * 16 + (lane & 15);
        ushort4 v;
        v.x = f2b(acc[i][j][0]); v.y = f2b(acc[i][j][1]);
        v.z = f2b(acc[i][j][2]); v.w = f2b(acc[i][j][3]);
        *(ushort4*)(Vh + (size_t)col * 2048 + rb) = v;   // 4 consecutive t -> 8B store
      }
    }
  }
}

// ---------------- flash attention (T14 async-stage + XCD swizzle, VGPR budget fixed) -----
// 1D grid 512; swz=(bid&7)*64+(bid>>3): XCD x owns heads {2x,2x+1} -> KV (2MB) L2-resident.
// 4 waves x 16 q-rows, KV tile 64. K[64][136], V^T[128][72], P[16][68]/wave.
// __launch_bounds__(256,2): LDS caps us at 2 blocks/CU anyway; give the allocator the
// full 256-VGPR budget so the 32-VGPR K/V prefetch stays in registers (R2 spilled at 76).
__global__ __launch_bounds__(256, 2) void attn_kernel(const u16* __restrict__ Qb,
                                                      const u16* __restrict__ Kb,
                                                      const u16* __restrict__ VTb,
                                                      u16* __restrict__ Rb) {
  __shared__ __align__(16) u16 Ks[64 * 136];
  __shared__ __align__(16) u16 Vs[128 * 72];
  __shared__ __align__(16) u16 Ps[4 * 16 * 68];
  int tid = threadIdx.x, lane = tid & 63, w = tid >> 6;
  int bid = blockIdx.x;
  int swz = (bid & 7) * 64 + (bid >> 3);
  int head = swz >> 5;
  int q0 = (swz & 31) * 64;
  const u16* Qh = Qb + (size_t)head * 2048 * 128;
  const u16* Kh = Kb + (size_t)head * 2048 * 128;
  const u16* Vh = VTb + (size_t)head * 128 * 2048;

  // Q fragments in registers for whole kernel (A layout: row=l&15, k contig)
  B8 q[4];
  {
    int qrow = q0 + w * 16 + (lane & 15);
#pragma unroll
    for (int ks = 0; ks < 4; ++ks)
      q[ks].u = *(const uint4*)(Qh + (size_t)qrow * 128 + ks * 32 + (lane >> 4) * 8);
  }

  // staging thread->element map (fixed per thread)
  const int krow = tid >> 4, kcol = (tid & 15) * 8;   // K: 16 thr/row, 16 rows/pass
  const int vrow = tid >> 3, vcol = (tid & 7) * 8;    // V^T: 8 thr/row, 32 rows/pass
  uint4 kreg[4], vreg[4];

  f32x4 o[8];
  f32x4 z4 = {0.f, 0.f, 0.f, 0.f};
#pragma unroll
  for (int f = 0; f < 8; ++f) o[f] = z4;
  float m_run[4] = {-1e30f, -1e30f, -1e30f, -1e30f};
  float l_run[4] = {0.f, 0.f, 0.f, 0.f};

  // prologue: stage tile 0
#pragma unroll
  for (int p = 0; p < 4; ++p) {
    kreg[p] = *(const uint4*)(Kh + (size_t)(p * 16 + krow) * 128 + kcol);
    vreg[p] = *(const uint4*)(Vh + (size_t)(p * 32 + vrow) * 2048 + vcol);
  }
#pragma unroll
  for (int p = 0; p < 4; ++p) {
    *(uint4*)(Ks + (p * 16 + krow) * 136 + kcol) = kreg[p];
    *(uint4*)(Vs + (p * 32 + vrow) * 72 + vcol) = vreg[p];
  }
  __syncthreads();

  u16* Pw = Ps + w * 16 * 68;
  for (int it = 0; it < 32; ++it) {
    int s1 = (it + 1) * 64;
    if (it < 31) {  // issue next K tile loads (awaited at the STORE below)
#pragma unroll
      for (int p = 0; p < 4; ++p)
        kreg[p] = *(const uint4*)(Kh + (size_t)(s1 + p * 16 + krow) * 128 + kcol);
    }

    // S = Q K^T (Q pre-scaled): 16 MFMA/wave
    f32x4 s[4];
#pragma unroll
    for (int f = 0; f < 4; ++f) s[f] = z4;
    __builtin_amdgcn_s_setprio(1);
#pragma unroll
    for (int f = 0; f < 4; ++f)
#pragma unroll
      for (int ks = 0; ks < 4; ++ks) {
        B8 kb;
        kb.u = *(const uint4*)(Ks + (f * 16 + (lane & 15)) * 136 + ks * 32 + (lane >> 4) * 8);
        s[f] = __builtin_amdgcn_mfma_f32_16x16x32_bf16(q[ks].b, kb.b, s[f], 0, 0, 0);
      }
    __builtin_amdgcn_s_setprio(0);

    if (it < 31) {  // issue next V tile loads (consumed next iter only)
#pragma unroll
      for (int p = 0; p < 4; ++p)
        vreg[p] = *(const uint4*)(Vh + (size_t)(p * 32 + vrow) * 2048 + s1 + vcol);
    }

    // online softmax; lane's rows = (l>>4)*4+i
    float mt[4];
#pragma unroll
    for (int i = 0; i < 4; ++i)
      mt[i] = fmaxf(fmaxf(s[0][i], s[1][i]), fmaxf(s[2][i], s[3][i]));
#pragma unroll
    for (int mask = 1; mask <= 8; mask <<= 1)
#pragma unroll
      for (int i = 0; i < 4; ++i) mt[i] = fmaxf(mt[i], __shfl_xor(mt[i], mask, 64));

    float al[4];
#pragma unroll
    for (int i = 0; i < 4; ++i) {
      float mn = fmaxf(m_run[i], mt[i]);
      al[i] = __expf(m_run[i] - mn);
      m_run[i] = mn;
    }
    float ps[4] = {0.f, 0.f, 0.f, 0.f};
#pragma unroll
    for (int f = 0; f < 4; ++f)
#pragma unroll
      for (int i = 0; i < 4; ++i) {
        float p = __expf(s[f][i] - m_run[i]);
        ps[i] += p;
        Pw[((lane >> 4) * 4 + i) * 68 + f * 16 + (lane & 15)] = f2b(p);
      }
#pragma unroll
    for (int mask = 1; mask <= 8; mask <<= 1)
#pragma unroll
      for (int i = 0; i < 4; ++i) ps[i] += __shfl_xor(ps[i], mask, 64);
#pragma unroll
    for (int i = 0; i < 4; ++i) l_run[i] = l_run[i] * al[i] + ps[i];

    // rescale O, then O += P*V (16 MFMA/wave)
#pragma unroll
    for (int f = 0; f < 8; ++f)
#pragma unroll
      for (int i = 0; i < 4; ++i) o[f][i] *= al[i];

    B8 pa[2];
#pragma unroll
    for (int k2 = 0; k2 < 2; ++k2) {
      const u16* pp = Pw + (lane & 15) * 68 + k2 * 32 + (lane >> 4) * 8;
      pa[k2].d[0] = *(const uint2*)(pp);
      pa[k2].d[1] = *(const uint2*)(pp + 4);
    }
    __builtin_amdgcn_s_setprio(1);
#pragma unroll
    for (int f = 0; f < 8; ++f)
#pragma unroll
      for (int k2 = 0; k2 < 2; ++k2) {
        B8 vb;
        vb.u = *(const uint4*)(Vs + (f * 16 + (lane & 15)) * 72 + k2 * 32 + (lane >> 4) * 8);
        o[f] = __builtin_amdgcn_mfma_f32_16x16x32_bf16(pa[k2].b, vb.b, o[f], 0, 0, 0);
      }
    __builtin_amdgcn_s_setprio(0);

    __syncthreads();  // all waves done reading Ks/Vs
    if (it < 31) {    // write prefetched tile (vmcnt wait lands here, latency hidden)
#pragma unroll
      for (int p = 0; p < 4; ++p) {
        *(uint4*)(Ks + (p * 16 + krow) * 136 + kcol) = kreg[p];
        *(uint4*)(Vs + (p * 32 + vrow) * 72 + vcol) = vreg[p];
      }
    }
    __syncthreads();  // new tile visible
  }

  // normalize and write R in (t, n*128+h) layout
#pragma unroll
  for (int i = 0; i < 4; ++i) {
    float inv = 1.0f / l_run[i];
    int row = q0 + w * 16 + (lane >> 4) * 4 + i;
#pragma unroll
    for (int f = 0; f < 8; ++f) {
      int col = head * 128 + f * 16 + (lane & 15);
      Rb[(size_t)row * 2048 + col] = f2b(o[f][i] * inv);
    }
  }
}

// ---------------- output projection: out = R(2048x2048) * W_out ----------------
__global__ __launch_bounds__(256) void out_gemm_kernel(const u16* __restrict__ Rb,
                                                       const u16* __restrict__ Wob,
                                                       float* __restrict__ out) {
  __shared__ __align__(16) u16 As[128 * 64];
  __shared__ __align__(16) u16 Bs[128 * 64];
  int tid = threadIdx.x;
  int o = blockIdx.x;
  int swz = (o & 7) * 32 + (o >> 3);
  int m0 = (swz & 15) * 128, n0 = (swz >> 4) * 128;
  f32x4 z = {0.f, 0.f, 0.f, 0.f};
  f32x4 acc[4][4];
#pragma unroll
  for (int i = 0; i < 4; ++i)
#pragma unroll
    for (int j = 0; j < 4; ++j) acc[i][j] = z;
  gemm_mainloop(Rb + (size_t)m0 * 2048, Wob + (size_t)n0 * 2048, As, Bs, acc, tid);

  int lane = tid & 63, wr = tid >> 7, wc = (tid >> 6) & 1;
#pragma unroll
  for (int i = 0; i < 4; ++i) {
    int rb = m0 + wr * 64 + i * 16 + (lane >> 4) * 4;
#pragma unroll
    for (int j = 0; j < 4; ++j) {
      int col = n0 + wc * 64 + j * 16 + (lane & 15);
#pragma unroll
      for (int r = 0; r < 4; ++r)
        out[(size_t)(rb + r) * 2048 + col] = acc[i][j][r];
    }
  }
}

extern "C" void kernel_launch(void* const* d_in, const int* in_sizes, int n_in,
                              void* d_out, int out_size, void* d_ws, size_t ws_size,
                              hipStream_t stream) {
  const float* X  = (const float*)d_in[0];
  const float* WQ = (const float*)d_in[1];
  const float* WK = (const float*)d_in[2];
  const float* WV = (const float*)d_in[3];
  const float* WO = (const float*)d_in[4];
  float* out = (float*)d_out;

  char* ws = (char*)d_ws;
  const size_t MB8 = 8u << 20;
  u16* Xb    = (u16*)(ws);
  u16* Wqkvb = (u16*)(ws + MB8);          // 3 x 8 MiB
  u16* Woutb = (u16*)(ws + 4 * MB8);
  u16* Qb    = (u16*)(ws + 5 * MB8);
  u16* Kb    = (u16*)(ws + 6 * MB8);
  u16* VTb   = (u16*)(ws + 7 * MB8);
  u16* Rbuf  = (u16*)(ws + MB8);          // aliases Wqkvb[W_Q]: dead after qkv_gemm

  cvt_x_kernel<<<dim3(4096), dim3(256), 0, stream>>>(X, Xb);
  tcvt_kernel<<<dim3(4, 64, 16), dim3(32, 8), 0, stream>>>(WQ, Wqkvb, 2048, 128);
  tcvt_kernel<<<dim3(4, 64, 16), dim3(32, 8), 0, stream>>>(WK, Wqkvb + (size_t)16 * 128 * 2048, 2048, 128);
  tcvt_kernel<<<dim3(4, 64, 16), dim3(32, 8), 0, stream>>>(WV, Wqkvb + (size_t)32 * 128 * 2048, 2048, 128);
  tcvt_kernel<<<dim3(64, 64, 1), dim3(32, 8), 0, stream>>>(WO, Woutb, 2048, 2048);

  qkv_gemm_kernel<<<dim3(768), dim3(256), 0, stream>>>(Xb, Wqkvb, Qb, Kb, VTb);
  attn_kernel<<<dim3(512), dim3(256), 0, stream>>>(Qb, Kb, VTb, Rbuf);
  out_gemm_kernel<<<dim3(256), dim3(256), 0, stream>>>(Rbuf, Woutb, out);
}

// Round 6
// 326.805 us; speedup vs baseline: 1.4428x; 1.2096x over previous
//
#include <hip/hip_runtime.h>

// MHSA: X(1,2048,2048) fp32; W_Q/K/V(16,2048,128); W_out(2048,2048); out (2048,2048) fp32.
// R6 = R5 resubmit (R5 bench was an infra failure, kernel never ran).
// attn staging is T3 "minimum 2-phase": double-buffered K/V in LDS filled by
// global_load_lds (async DMA, zero VGPRs -> no spill possible; R2/R4 reg-prefetch spilled
// ~200MB scratch), T2 XOR-swizzle via pre-swizzled global source, ONE barrier/iter.
// XCD swizzle keeps 2 heads/XCD so KV stays L2-resident (R3 proved FETCH=essential).
// Workspace layout (needs 64 MiB): see round 0 comment (unchanged).

typedef unsigned short u16;
typedef __bf16 bf16x8 __attribute__((ext_vector_type(8)));
typedef float f32x4 __attribute__((ext_vector_type(4)));
typedef __attribute__((address_space(1))) void gvoid;
typedef __attribute__((address_space(3))) void svoid;

union B8 { uint4 u; uint2 d[2]; bf16x8 b; };

__device__ __forceinline__ u16 f2b(float f) {
  unsigned int u = __float_as_uint(f);
  unsigned int r = (u + 0x7FFFu + ((u >> 16) & 1u)) >> 16;  // RNE
  return (u16)r;
}

// ---------------- convert X: fp32 -> bf16, 4 elems/thread ----------------
__global__ __launch_bounds__(256) void cvt_x_kernel(const float* __restrict__ x,
                                                    u16* __restrict__ xb) {
  int i = (blockIdx.x * 256 + threadIdx.x) * 4;
  float4 v = *(const float4*)(x + i);
  ushort4 o;
  o.x = f2b(v.x); o.y = f2b(v.y); o.z = f2b(v.z); o.w = f2b(v.w);
  *(ushort4*)(xb + i) = o;
}

// ------- transpose+convert: src (batch,K,N) f32 -> dst (batch,N,K) bf16 -------
__global__ __launch_bounds__(256) void tcvt_kernel(const float* __restrict__ src,
                                                   u16* __restrict__ dst, int K, int N) {
  __shared__ float t[32][33];
  int bz = blockIdx.z;
  int n0 = blockIdx.x * 32, k0 = blockIdx.y * 32;
  const float* S = src + (size_t)bz * K * N;
  u16* D = dst + (size_t)bz * K * N;
  int tx = threadIdx.x, ty = threadIdx.y;  // (32,8)
#pragma unroll
  for (int d = 0; d < 4; ++d)
    t[ty + d * 8][tx] = S[(size_t)(k0 + ty + d * 8) * N + n0 + tx];
  __syncthreads();
#pragma unroll
  for (int d = 0; d < 4; ++d)
    D[(size_t)(n0 + ty + d * 8) * K + k0 + tx] = f2b(t[tx][ty + d * 8]);
}

// ---------------- shared GEMM mainloop: C(128x128) = A(128x2048) * B^T(128x2048)^T --------
// LDS tiles [128][64] bf16, XOR-swizzled (byte ^= ((byte>>7)&7)<<4); global_load_lds
// writes linearly -> source addresses pre-inverse-swizzled (m173/m201 pattern).
__device__ __forceinline__ void gemm_mainloop(const u16* Ag, const u16* Bg,
                                              u16* As, u16* Bs,
                                              f32x4 acc[4][4], int tid) {
  const int lane = tid & 63;
  const int wr = tid >> 7, wc = (tid >> 6) & 1;  // 4 waves in 2x2, wave tile 64x64
  for (int k0 = 0; k0 < 2048; k0 += 64) {
    __syncthreads();  // previous iter's reads done before overwrite
#pragma unroll
    for (int it = 0; it < 4; ++it) {
      int s = it * 256 + tid;
      int pb = s * 16;                           // physical (linear) LDS byte
      int lb = pb ^ ((((pb) >> 7) & 7) << 4);    // logical byte (involution)
      int row = lb >> 7;                         // 0..127
      int k8 = (lb >> 4) & 7;                    // 16B granule within row
      const u16* ga = Ag + (size_t)row * 2048 + k0 + k8 * 8;
      const u16* gb = Bg + (size_t)row * 2048 + k0 + k8 * 8;
      char* la = (char*)As + it * 4096 + (tid & 192) * 16;  // wave-uniform base
      char* lb2 = (char*)Bs + it * 4096 + (tid & 192) * 16;
      __builtin_amdgcn_global_load_lds((gvoid*)(void*)ga, (svoid*)la, 16, 0, 0);
      __builtin_amdgcn_global_load_lds((gvoid*)(void*)gb, (svoid*)lb2, 16, 0, 0);
    }
    __syncthreads();
#pragma unroll
    for (int ks = 0; ks < 2; ++ks) {
      B8 a[4], b[4];
#pragma unroll
      for (int i = 0; i < 4; ++i) {
        int rowa = wr * 64 + i * 16 + (lane & 15);
        int ba = rowa * 128 + ks * 64 + (lane >> 4) * 16;
        ba ^= (rowa & 7) << 4;
        a[i].u = *(const uint4*)((const char*)As + ba);
        int rowb = wc * 64 + i * 16 + (lane & 15);
        int bb = rowb * 128 + ks * 64 + (lane >> 4) * 16;
        bb ^= (rowb & 7) << 4;
        b[i].u = *(const uint4*)((const char*)Bs + bb);
      }
      __builtin_amdgcn_s_setprio(1);
#pragma unroll
      for (int i = 0; i < 4; ++i)
#pragma unroll
        for (int j = 0; j < 4; ++j)
          acc[i][j] = __builtin_amdgcn_mfma_f32_16x16x32_bf16(a[i].b, b[j].b, acc[i][j], 0, 0, 0);
      __builtin_amdgcn_s_setprio(0);
    }
  }
}

// ---------------- fused QKV projection ----------------
// 1D grid 768 blocks; XCD swizzle: each XCD gets 6 col-tiles x all 16 m-tiles.
__global__ __launch_bounds__(256) void qkv_gemm_kernel(const u16* __restrict__ Xb,
                                                       const u16* __restrict__ Wb,
                                                       u16* __restrict__ Qb,
                                                       u16* __restrict__ Kb,
                                                       u16* __restrict__ VTb) {
  __shared__ __align__(16) u16 As[128 * 64];
  __shared__ __align__(16) u16 Bs[128 * 64];
  int tid = threadIdx.x;
  int o = blockIdx.x;
  int swz = (o & 7) * 96 + (o >> 3);
  int m0 = (swz & 15) * 128;
  int c0 = swz >> 4;             // 0..47
  int tau = c0 >> 4, head = c0 & 15;
  f32x4 z = {0.f, 0.f, 0.f, 0.f};
  f32x4 acc[4][4];
#pragma unroll
  for (int i = 0; i < 4; ++i)
#pragma unroll
    for (int j = 0; j < 4; ++j) acc[i][j] = z;
  gemm_mainloop(Xb + (size_t)m0 * 2048, Wb + (size_t)c0 * 128 * 2048, As, Bs, acc, tid);

  int lane = tid & 63, wr = tid >> 7, wc = (tid >> 6) & 1;
  if (tau < 2) {
    u16* Oh = ((tau == 0) ? Qb : Kb) + (size_t)head * 2048 * 128;
    float sc = (tau == 0) ? 0.08838834764831845f : 1.0f;  // fold 1/sqrt(128) into Q
#pragma unroll
    for (int i = 0; i < 4; ++i) {
      int rb = m0 + wr * 64 + i * 16 + (lane >> 4) * 4;  // C layout: row=(l>>4)*4+r
#pragma unroll
      for (int j = 0; j < 4; ++j) {
        int col = wc * 64 + j * 16 + (lane & 15);        // C layout: col=l&15
#pragma unroll
        for (int r = 0; r < 4; ++r)
          Oh[(size_t)(rb + r) * 128 + col] = f2b(acc[i][j][r] * sc);
      }
    }
  } else {  // V: store transposed (h, t) so PV B-operand is k-contiguous
    u16* Vh = VTb + (size_t)head * 128 * 2048;
#pragma unroll
    for (int i = 0; i < 4; ++i) {
      int rb = m0 + wr * 64 + i * 16 + (lane >> 4) * 4;
#pragma unroll
      for (int j = 0; j < 4; ++j) {
        int col = wc * 64 + j * 16 + (lane & 15);
        ushort4 v;
        v.x = f2b(acc[i][j][0]); v.y = f2b(acc[i][j][1]);
        v.z = f2b(acc[i][j][2]); v.w = f2b(acc[i][j][3]);
        *(ushort4*)(Vh + (size_t)col * 2048 + rb) = v;   // 4 consecutive t -> 8B store
      }
    }
  }
}

// ---------------- flash attention (dbuf global_load_lds staging, 1 barrier/iter) ---------
// 1D grid 512; swz=(bid&7)*64+(bid>>3): XCD x owns heads {2x,2x+1} -> KV (2MB) L2-resident.
// 4 waves x 16 q-rows, KV tile 64.
// K LDS tile: logical [64][128] u16 (row=256B), phys byte = lb ^ (((lb>>8)&7)<<4).
// V^T LDS tile: logical [128][64] u16 (row=128B), phys byte = lb ^ (((lb>>7)&7)<<4).
// global_load_lds writes linearly; the global SOURCE address is pre-inverse-swizzled.
// P transpose scratch [16][68]/wave is per-wave (no barrier needed).
__global__ __launch_bounds__(256, 2) void attn_kernel(const u16* __restrict__ Qb,
                                                      const u16* __restrict__ Kb,
                                                      const u16* __restrict__ VTb,
                                                      u16* __restrict__ Rb) {
  __shared__ __align__(16) u16 Ks[2][64 * 128];
  __shared__ __align__(16) u16 Vs[2][128 * 64];
  __shared__ __align__(16) u16 Ps[4 * 16 * 68];
  int tid = threadIdx.x, lane = tid & 63, w = tid >> 6;
  int bid = blockIdx.x;
  int swz = (bid & 7) * 64 + (bid >> 3);
  int head = swz >> 5;
  int q0 = (swz & 31) * 64;
  const u16* Qh = Qb + (size_t)head * 2048 * 128;
  const u16* Kh = Kb + (size_t)head * 2048 * 128;
  const u16* Vh = VTb + (size_t)head * 128 * 2048;

  // Q fragments in registers for whole kernel (A layout: row=l&15, k contig)
  B8 q[4];
  {
    int qrow = q0 + w * 16 + (lane & 15);
#pragma unroll
    for (int ks = 0; ks < 4; ++ks)
      q[ks].u = *(const uint4*)(Qh + (size_t)qrow * 128 + ks * 32 + (lane >> 4) * 8);
  }

  f32x4 o[8];
  f32x4 z4 = {0.f, 0.f, 0.f, 0.f};
#pragma unroll
  for (int f = 0; f < 8; ++f) o[f] = z4;
  float m_run[4] = {-1e30f, -1e30f, -1e30f, -1e30f};
  float l_run[4] = {0.f, 0.f, 0.f, 0.f};

  // ---- async stage of one K/V tile (s0 = t-offset) into buffer bi ----
  auto STAGE = [&](int bi, int s0) {
#pragma unroll
    for (int it2 = 0; it2 < 4; ++it2) {
      int pb = (it2 * 256 + tid) * 16;            // physical (linear) LDS byte
      // K: logical row stride 256B, swizzle bits 4-6 by row&7
      int lbK = pb ^ (((pb >> 8) & 7) << 4);
      int rowK = lbK >> 8;                        // 0..63
      int k8 = (lbK >> 4) & 15;                   // 16B granule within row
      const u16* gk = Kh + (size_t)(s0 + rowK) * 128 + k8 * 8;
      char* dk = (char*)Ks[bi] + it2 * 4096 + (tid & 192) * 16;  // wave-uniform base
      __builtin_amdgcn_global_load_lds((gvoid*)(void*)gk, (svoid*)dk, 16, 0, 0);
      // V^T: logical row stride 128B, swizzle bits 4-6 by row&7
      int lbV = pb ^ (((pb >> 7) & 7) << 4);
      int rowV = lbV >> 7;                        // 0..127
      int t8 = (lbV >> 4) & 7;
      const u16* gv = Vh + (size_t)rowV * 2048 + s0 + t8 * 8;
      char* dv = (char*)Vs[bi] + it2 * 4096 + (tid & 192) * 16;
      __builtin_amdgcn_global_load_lds((gvoid*)(void*)gv, (svoid*)dv, 16, 0, 0);
    }
  };

  STAGE(0, 0);
  __syncthreads();  // vmcnt drained by compiler before barrier -> tile 0 ready

  u16* Pw = Ps + w * 16 * 68;
  for (int it = 0; it < 32; ++it) {
    int cur = it & 1;
    if (it < 31) STAGE(cur ^ 1, (it + 1) * 64);  // in flight during compute below

    // ---- S = Q K^T (Q pre-scaled): 16 MFMA/wave ----
    f32x4 s[4];
#pragma unroll
    for (int f = 0; f < 4; ++f) s[f] = z4;
    __builtin_amdgcn_s_setprio(1);
#pragma unroll
    for (int f = 0; f < 4; ++f) {
      int r = f * 16 + (lane & 15);
#pragma unroll
      for (int ks = 0; ks < 4; ++ks) {
        int lb = r * 256 + ks * 64 + (lane >> 4) * 16;
        B8 kb;
        kb.u = *(const uint4*)((const char*)Ks[cur] + (lb ^ ((r & 7) << 4)));
        s[f] = __builtin_amdgcn_mfma_f32_16x16x32_bf16(q[ks].b, kb.b, s[f], 0, 0, 0);
      }
    }
    __builtin_amdgcn_s_setprio(0);

    // ---- online softmax; lane's rows = (l>>4)*4+i ----
    float mt[4];
#pragma unroll
    for (int i = 0; i < 4; ++i)
      mt[i] = fmaxf(fmaxf(s[0][i], s[1][i]), fmaxf(s[2][i], s[3][i]));
#pragma unroll
    for (int mask = 1; mask <= 8; mask <<= 1)
#pragma unroll
      for (int i = 0; i < 4; ++i) mt[i] = fmaxf(mt[i], __shfl_xor(mt[i], mask, 64));

    float al[4];
#pragma unroll
    for (int i = 0; i < 4; ++i) {
      float mn = fmaxf(m_run[i], mt[i]);
      al[i] = __expf(m_run[i] - mn);
      m_run[i] = mn;
    }
    float ps[4] = {0.f, 0.f, 0.f, 0.f};
#pragma unroll
    for (int f = 0; f < 4; ++f)
#pragma unroll
      for (int i = 0; i < 4; ++i) {
        float p = __expf(s[f][i] - m_run[i]);
        ps[i] += p;
        Pw[((lane >> 4) * 4 + i) * 68 + f * 16 + (lane & 15)] = f2b(p);
      }
#pragma unroll
    for (int mask = 1; mask <= 8; mask <<= 1)
#pragma unroll
      for (int i = 0; i < 4; ++i) ps[i] += __shfl_xor(ps[i], mask, 64);
#pragma unroll
    for (int i = 0; i < 4; ++i) l_run[i] = l_run[i] * al[i] + ps[i];

    // ---- rescale O, then O += P*V (16 MFMA/wave) ----
#pragma unroll
    for (int f = 0; f < 8; ++f)
#pragma unroll
      for (int i = 0; i < 4; ++i) o[f][i] *= al[i];

    B8 pa[2];
#pragma unroll
    for (int k2 = 0; k2 < 2; ++k2) {
      const u16* pp = Pw + (lane & 15) * 68 + k2 * 32 + (lane >> 4) * 8;
      pa[k2].d[0] = *(const uint2*)(pp);
      pa[k2].d[1] = *(const uint2*)(pp + 4);
    }
    __builtin_amdgcn_s_setprio(1);
#pragma unroll
    for (int f = 0; f < 8; ++f) {
      int r = f * 16 + (lane & 15);
#pragma unroll
      for (int k2 = 0; k2 < 2; ++k2) {
        int lb = r * 128 + k2 * 64 + (lane >> 4) * 16;
        B8 vb;
        vb.u = *(const uint4*)((const char*)Vs[cur] + (lb ^ ((r & 7) << 4)));
        o[f] = __builtin_amdgcn_mfma_f32_16x16x32_bf16(pa[k2].b, vb.b, o[f], 0, 0, 0);
      }
    }
    __builtin_amdgcn_s_setprio(0);

    __syncthreads();  // drains stage vmcnt; next tile ready, cur buffer reusable
  }

  // normalize and write R in (t, n*128+h) layout
#pragma unroll
  for (int i = 0; i < 4; ++i) {
    float inv = 1.0f / l_run[i];
    int row = q0 + w * 16 + (lane >> 4) * 4 + i;
#pragma unroll
    for (int f = 0; f < 8; ++f) {
      int col = head * 128 + f * 16 + (lane & 15);
      Rb[(size_t)row * 2048 + col] = f2b(o[f][i] * inv);
    }
  }
}

// ---------------- output projection: out = R(2048x2048) * W_out ----------------
__global__ __launch_bounds__(256) void out_gemm_kernel(const u16* __restrict__ Rb,
                                                       const u16* __restrict__ Wob,
                                                       float* __restrict__ out) {
  __shared__ __align__(16) u16 As[128 * 64];
  __shared__ __align__(16) u16 Bs[128 * 64];
  int tid = threadIdx.x;
  int o = blockIdx.x;
  int swz = (o & 7) * 32 + (o >> 3);
  int m0 = (swz & 15) * 128, n0 = (swz >> 4) * 128;
  f32x4 z = {0.f, 0.f, 0.f, 0.f};
  f32x4 acc[4][4];
#pragma unroll
  for (int i = 0; i < 4; ++i)
#pragma unroll
    for (int j = 0; j < 4; ++j) acc[i][j] = z;
  gemm_mainloop(Rb + (size_t)m0 * 2048, Wob + (size_t)n0 * 2048, As, Bs, acc, tid);

  int lane = tid & 63, wr = tid >> 7, wc = (tid >> 6) & 1;
#pragma unroll
  for (int i = 0; i < 4; ++i) {
    int rb = m0 + wr * 64 + i * 16 + (lane >> 4) * 4;
#pragma unroll
    for (int j = 0; j < 4; ++j) {
      int col = n0 + wc * 64 + j * 16 + (lane & 15);
#pragma unroll
      for (int r = 0; r < 4; ++r)
        out[(size_t)(rb + r) * 2048 + col] = acc[i][j][r];
    }
  }
}

extern "C" void kernel_launch(void* const* d_in, const int* in_sizes, int n_in,
                              void* d_out, int out_size, void* d_ws, size_t ws_size,
                              hipStream_t stream) {
  const float* X  = (const float*)d_in[0];
  const float* WQ = (const float*)d_in[1];
  const float* WK = (const float*)d_in[2];
  const float* WV = (const float*)d_in[3];
  const float* WO = (const float*)d_in[4];
  float* out = (float*)d_out;

  char* ws = (char*)d_ws;
  const size_t MB8 = 8u << 20;
  u16* Xb    = (u16*)(ws);
  u16* Wqkvb = (u16*)(ws + MB8);          // 3 x 8 MiB
  u16* Woutb = (u16*)(ws + 4 * MB8);
  u16* Qb    = (u16*)(ws + 5 * MB8);
  u16* Kb    = (u16*)(ws + 6 * MB8);
  u16* VTb   = (u16*)(ws + 7 * MB8);
  u16* Rbuf  = (u16*)(ws + MB8);          // aliases Wqkvb[W_Q]: dead after qkv_gemm

  cvt_x_kernel<<<dim3(4096), dim3(256), 0, stream>>>(X, Xb);
  tcvt_kernel<<<dim3(4, 64, 16), dim3(32, 8), 0, stream>>>(WQ, Wqkvb, 2048, 128);
  tcvt_kernel<<<dim3(4, 64, 16), dim3(32, 8), 0, stream>>>(WK, Wqkvb + (size_t)16 * 128 * 2048, 2048, 128);
  tcvt_kernel<<<dim3(4, 64, 16), dim3(32, 8), 0, stream>>>(WV, Wqkvb + (size_t)32 * 128 * 2048, 2048, 128);
  tcvt_kernel<<<dim3(64, 64, 1), dim3(32, 8), 0, stream>>>(WO, Woutb, 2048, 2048);

  qkv_gemm_kernel<<<dim3(768), dim3(256), 0, stream>>>(Xb, Wqkvb, Qb, Kb, VTb);
  attn_kernel<<<dim3(512), dim3(256), 0, stream>>>(Qb, Kb, VTb, Rbuf);
  out_gemm_kernel<<<dim3(256), dim3(256), 0, stream>>>(Rbuf, Woutb, out);
}

// Round 7
// 315.897 us; speedup vs baseline: 1.4926x; 1.0345x over previous
//
#include <hip/hip_runtime.h>

// MHSA: X(1,2048,2048) fp32; W_Q/K/V(16,2048,128); W_out(2048,2048); out (2048,2048) fp32.
// R7: (1) all 5 prep kernels (cvt_x + 4 transpose-cvt) fused into ONE launch (saves ~4
// launch gaps); (2) out_gemm gets double-buffered overlap staging (it runs at 1 block/CU
// where cross-block latency hiding doesn't exist; qkv at 3 blocks/CU keeps the proven
// m97 structure — dbuf measured null there). attn unchanged from R6 (91.5us, spill-free).
// Workspace layout (needs 64 MiB): see round 0 comment (unchanged).

typedef unsigned short u16;
typedef __bf16 bf16x8 __attribute__((ext_vector_type(8)));
typedef float f32x4 __attribute__((ext_vector_type(4)));
typedef __attribute__((address_space(1))) void gvoid;
typedef __attribute__((address_space(3))) void svoid;

union B8 { uint4 u; uint2 d[2]; bf16x8 b; };

__device__ __forceinline__ u16 f2b(float f) {
  unsigned int u = __float_as_uint(f);
  unsigned int r = (u + 0x7FFFu + ((u >> 16) & 1u)) >> 16;  // RNE
  return (u16)r;
}

// ---------------- fused prep: cvt X + transpose-cvt all W ----------------
// 20480 blocks x 256 thr. seg = bid>>12: 0=cvt_x, 1/2/3=W_Q/K/V (per-head 2048x128
// transpose), 4=W_out (2048x2048 transpose). All segments use 32x32 LDS tiles for the
// transposes; cvt_x is a flat float4->ushort4 stream.
__global__ __launch_bounds__(256) void prep_kernel(const float* __restrict__ X,
                                                   const float* __restrict__ WQ,
                                                   const float* __restrict__ WK,
                                                   const float* __restrict__ WV,
                                                   const float* __restrict__ WO,
                                                   u16* __restrict__ Xb,
                                                   u16* __restrict__ Wqkvb,
                                                   u16* __restrict__ Woutb) {
  int bid = blockIdx.x;
  int seg = bid >> 12;       // 0..4
  int sub = bid & 4095;
  int tid = threadIdx.x;
  if (seg == 0) {            // cvt_x: 4096 blocks * 1024 elems
    int i = (sub * 256 + tid) * 4;
    float4 v = *(const float4*)(X + i);
    ushort4 o;
    o.x = f2b(v.x); o.y = f2b(v.y); o.z = f2b(v.z); o.w = f2b(v.w);
    *(ushort4*)(Xb + i) = o;
    return;
  }
  __shared__ float t[32][33];
  const float* S;
  u16* D;
  int N, n0, k0;
  if (seg <= 3) {            // W_Q/K/V: per head K=2048 x N=128 -> (head, 128, 2048)
    const float* W = (seg == 1) ? WQ : (seg == 2) ? WK : WV;
    int head = sub >> 8, rest = sub & 255;
    N = 128;
    S = W + (size_t)head * 2048 * 128;
    D = Wqkvb + (size_t)(seg - 1) * 16 * 2048 * 128 + (size_t)head * 2048 * 128;
    n0 = (rest & 3) * 32;
    k0 = (rest >> 2) * 32;
  } else {                   // W_out: 2048x2048 -> 2048x2048 transposed
    N = 2048;
    S = WO;
    D = Woutb;
    n0 = (sub & 63) * 32;
    k0 = (sub >> 6) * 32;
  }
  int tx = tid & 31, ty = tid >> 5;  // (32,8)
#pragma unroll
  for (int d = 0; d < 4; ++d)
    t[ty + d * 8][tx] = S[(size_t)(k0 + ty + d * 8) * N + n0 + tx];
  __syncthreads();
#pragma unroll
  for (int d = 0; d < 4; ++d)
    D[(size_t)(n0 + ty + d * 8) * 2048 + k0 + tx] = f2b(t[tx][ty + d * 8]);
}

// ---------------- GEMM building blocks: 128x128 tile, BK=64 --------------------
// LDS tiles [128][64] bf16, XOR-swizzled (byte ^= ((byte>>7)&7)<<4); global_load_lds
// writes linearly -> source addresses pre-inverse-swizzled (m173/m201 pattern).
__device__ __forceinline__ void stage_tile(const u16* Ag, const u16* Bg,
                                           u16* As, u16* Bs, int k0, int tid) {
#pragma unroll
  for (int it = 0; it < 4; ++it) {
    int s = it * 256 + tid;
    int pb = s * 16;                           // physical (linear) LDS byte
    int lb = pb ^ ((((pb) >> 7) & 7) << 4);    // logical byte (involution)
    int row = lb >> 7;                         // 0..127
    int k8 = (lb >> 4) & 7;                    // 16B granule within row
    const u16* ga = Ag + (size_t)row * 2048 + k0 + k8 * 8;
    const u16* gb = Bg + (size_t)row * 2048 + k0 + k8 * 8;
    char* la = (char*)As + it * 4096 + (tid & 192) * 16;  // wave-uniform base
    char* lb2 = (char*)Bs + it * 4096 + (tid & 192) * 16;
    __builtin_amdgcn_global_load_lds((gvoid*)(void*)ga, (svoid*)la, 16, 0, 0);
    __builtin_amdgcn_global_load_lds((gvoid*)(void*)gb, (svoid*)lb2, 16, 0, 0);
  }
}

__device__ __forceinline__ void compute_tile(const u16* As, const u16* Bs,
                                             f32x4 acc[4][4], int lane, int wr, int wc) {
#pragma unroll
  for (int ks = 0; ks < 2; ++ks) {
    B8 a[4], b[4];
#pragma unroll
    for (int i = 0; i < 4; ++i) {
      int rowa = wr * 64 + i * 16 + (lane & 15);
      int ba = rowa * 128 + ks * 64 + (lane >> 4) * 16;
      ba ^= (rowa & 7) << 4;
      a[i].u = *(const uint4*)((const char*)As + ba);
      int rowb = wc * 64 + i * 16 + (lane & 15);
      int bb = rowb * 128 + ks * 64 + (lane >> 4) * 16;
      bb ^= (rowb & 7) << 4;
      b[i].u = *(const uint4*)((const char*)Bs + bb);
    }
    __builtin_amdgcn_s_setprio(1);
#pragma unroll
    for (int i = 0; i < 4; ++i)
#pragma unroll
      for (int j = 0; j < 4; ++j)
        acc[i][j] = __builtin_amdgcn_mfma_f32_16x16x32_bf16(a[i].b, b[j].b, acc[i][j], 0, 0, 0);
    __builtin_amdgcn_s_setprio(0);
  }
}

// single-buffer mainloop (m97 structure) — used by qkv (3 blocks/CU: cross-block
// wave overlap already hides staging; dbuf measured null at this occupancy).
__device__ __forceinline__ void gemm_mainloop(const u16* Ag, const u16* Bg,
                                              u16* As, u16* Bs,
                                              f32x4 acc[4][4], int tid) {
  const int lane = tid & 63;
  const int wr = tid >> 7, wc = (tid >> 6) & 1;  // 4 waves in 2x2, wave tile 64x64
  for (int k0 = 0; k0 < 2048; k0 += 64) {
    __syncthreads();  // previous iter's reads done before overwrite
    stage_tile(Ag, Bg, As, Bs, k0, tid);
    __syncthreads();
    compute_tile(As, Bs, acc, lane, wr, wc);
  }
}

// double-buffered mainloop — used by out_gemm (1 block/CU: no cross-block hiding,
// so STAGE(next) must overlap compute(cur)). One barrier per iter drains the stage.
__device__ __forceinline__ void gemm_mainloop_dbuf(const u16* Ag, const u16* Bg,
                                                   u16* As0, u16* Bs0, u16* As1, u16* Bs1,
                                                   f32x4 acc[4][4], int tid) {
  const int lane = tid & 63;
  const int wr = tid >> 7, wc = (tid >> 6) & 1;
  stage_tile(Ag, Bg, As0, Bs0, 0, tid);
  __syncthreads();  // tile 0 ready
  for (int i = 0; i < 32; ++i) {
    u16* Ac = (i & 1) ? As1 : As0;
    u16* Bc = (i & 1) ? Bs1 : Bs0;
    u16* An = (i & 1) ? As0 : As1;
    u16* Bn = (i & 1) ? Bs0 : Bs1;
    if (i < 31) stage_tile(Ag, Bg, An, Bn, (i + 1) * 64, tid);  // async, in flight
    compute_tile(Ac, Bc, acc, lane, wr, wc);
    __syncthreads();  // drains stage vmcnt; next tile ready, cur reusable
  }
}

// ---------------- fused QKV projection ----------------
// 1D grid 768 blocks; XCD swizzle: each XCD gets 6 col-tiles x all 16 m-tiles.
__global__ __launch_bounds__(256) void qkv_gemm_kernel(const u16* __restrict__ Xb,
                                                       const u16* __restrict__ Wb,
                                                       u16* __restrict__ Qb,
                                                       u16* __restrict__ Kb,
                                                       u16* __restrict__ VTb) {
  __shared__ __align__(16) u16 As[128 * 64];
  __shared__ __align__(16) u16 Bs[128 * 64];
  int tid = threadIdx.x;
  int o = blockIdx.x;
  int swz = (o & 7) * 96 + (o >> 3);
  int m0 = (swz & 15) * 128;
  int c0 = swz >> 4;             // 0..47
  int tau = c0 >> 4, head = c0 & 15;
  f32x4 z = {0.f, 0.f, 0.f, 0.f};
  f32x4 acc[4][4];
#pragma unroll
  for (int i = 0; i < 4; ++i)
#pragma unroll
    for (int j = 0; j < 4; ++j) acc[i][j] = z;
  gemm_mainloop(Xb + (size_t)m0 * 2048, Wb + (size_t)c0 * 128 * 2048, As, Bs, acc, tid);

  int lane = tid & 63, wr = tid >> 7, wc = (tid >> 6) & 1;
  if (tau < 2) {
    u16* Oh = ((tau == 0) ? Qb : Kb) + (size_t)head * 2048 * 128;
    float sc = (tau == 0) ? 0.08838834764831845f : 1.0f;  // fold 1/sqrt(128) into Q
#pragma unroll
    for (int i = 0; i < 4; ++i) {
      int rb = m0 + wr * 64 + i * 16 + (lane >> 4) * 4;  // C layout: row=(l>>4)*4+r
#pragma unroll
      for (int j = 0; j < 4; ++j) {
        int col = wc * 64 + j * 16 + (lane & 15);        // C layout: col=l&15
#pragma unroll
        for (int r = 0; r < 4; ++r)
          Oh[(size_t)(rb + r) * 128 + col] = f2b(acc[i][j][r] * sc);
      }
    }
  } else {  // V: store transposed (h, t) so PV B-operand is k-contiguous
    u16* Vh = VTb + (size_t)head * 128 * 2048;
#pragma unroll
    for (int i = 0; i < 4; ++i) {
      int rb = m0 + wr * 64 + i * 16 + (lane >> 4) * 4;
#pragma unroll
      for (int j = 0; j < 4; ++j) {
        int col = wc * 64 + j * 16 + (lane & 15);
        ushort4 v;
        v.x = f2b(acc[i][j][0]); v.y = f2b(acc[i][j][1]);
        v.z = f2b(acc[i][j][2]); v.w = f2b(acc[i][j][3]);
        *(ushort4*)(Vh + (size_t)col * 2048 + rb) = v;   // 4 consecutive t -> 8B store
      }
    }
  }
}

// ---------------- flash attention (dbuf global_load_lds staging, 1 barrier/iter) ---------
// 1D grid 512; swz=(bid&7)*64+(bid>>3): XCD x owns heads {2x,2x+1} -> KV (2MB) L2-resident.
// 4 waves x 16 q-rows, KV tile 64.
// K LDS tile: logical [64][128] u16 (row=256B), phys byte = lb ^ (((lb>>8)&7)<<4).
// V^T LDS tile: logical [128][64] u16 (row=128B), phys byte = lb ^ (((lb>>7)&7)<<4).
// global_load_lds writes linearly; the global SOURCE address is pre-inverse-swizzled.
// P transpose scratch [16][68]/wave is per-wave (no barrier needed).
__global__ __launch_bounds__(256, 2) void attn_kernel(const u16* __restrict__ Qb,
                                                      const u16* __restrict__ Kb,
                                                      const u16* __restrict__ VTb,
                                                      u16* __restrict__ Rb) {
  __shared__ __align__(16) u16 Ks[2][64 * 128];
  __shared__ __align__(16) u16 Vs[2][128 * 64];
  __shared__ __align__(16) u16 Ps[4 * 16 * 68];
  int tid = threadIdx.x, lane = tid & 63, w = tid >> 6;
  int bid = blockIdx.x;
  int swz = (bid & 7) * 64 + (bid >> 3);
  int head = swz >> 5;
  int q0 = (swz & 31) * 64;
  const u16* Qh = Qb + (size_t)head * 2048 * 128;
  const u16* Kh = Kb + (size_t)head * 2048 * 128;
  const u16* Vh = VTb + (size_t)head * 128 * 2048;

  // Q fragments in registers for whole kernel (A layout: row=l&15, k contig)
  B8 q[4];
  {
    int qrow = q0 + w * 16 + (lane & 15);
#pragma unroll
    for (int ks = 0; ks < 4; ++ks)
      q[ks].u = *(const uint4*)(Qh + (size_t)qrow * 128 + ks * 32 + (lane >> 4) * 8);
  }

  f32x4 o[8];
  f32x4 z4 = {0.f, 0.f, 0.f, 0.f};
#pragma unroll
  for (int f = 0; f < 8; ++f) o[f] = z4;
  float m_run[4] = {-1e30f, -1e30f, -1e30f, -1e30f};
  float l_run[4] = {0.f, 0.f, 0.f, 0.f};

  // ---- async stage of one K/V tile (s0 = t-offset) into buffer bi ----
  auto STAGE = [&](int bi, int s0) {
#pragma unroll
    for (int it2 = 0; it2 < 4; ++it2) {
      int pb = (it2 * 256 + tid) * 16;            // physical (linear) LDS byte
      // K: logical row stride 256B, swizzle bits 4-6 by row&7
      int lbK = pb ^ (((pb >> 8) & 7) << 4);
      int rowK = lbK >> 8;                        // 0..63
      int k8 = (lbK >> 4) & 15;                   // 16B granule within row
      const u16* gk = Kh + (size_t)(s0 + rowK) * 128 + k8 * 8;
      char* dk = (char*)Ks[bi] + it2 * 4096 + (tid & 192) * 16;  // wave-uniform base
      __builtin_amdgcn_global_load_lds((gvoid*)(void*)gk, (svoid*)dk, 16, 0, 0);
      // V^T: logical row stride 128B, swizzle bits 4-6 by row&7
      int lbV = pb ^ (((pb >> 7) & 7) << 4);
      int rowV = lbV >> 7;                        // 0..127
      int t8 = (lbV >> 4) & 7;
      const u16* gv = Vh + (size_t)rowV * 2048 + s0 + t8 * 8;
      char* dv = (char*)Vs[bi] + it2 * 4096 + (tid & 192) * 16;
      __builtin_amdgcn_global_load_lds((gvoid*)(void*)gv, (svoid*)dv, 16, 0, 0);
    }
  };

  STAGE(0, 0);
  __syncthreads();  // vmcnt drained by compiler before barrier -> tile 0 ready

  u16* Pw = Ps + w * 16 * 68;
  for (int it = 0; it < 32; ++it) {
    int cur = it & 1;
    if (it < 31) STAGE(cur ^ 1, (it + 1) * 64);  // in flight during compute below

    // ---- S = Q K^T (Q pre-scaled): 16 MFMA/wave ----
    f32x4 s[4];
#pragma unroll
    for (int f = 0; f < 4; ++f) s[f] = z4;
    __builtin_amdgcn_s_setprio(1);
#pragma unroll
    for (int f = 0; f < 4; ++f) {
      int r = f * 16 + (lane & 15);
#pragma unroll
      for (int ks = 0; ks < 4; ++ks) {
        int lb = r * 256 + ks * 64 + (lane >> 4) * 16;
        B8 kb;
        kb.u = *(const uint4*)((const char*)Ks[cur] + (lb ^ ((r & 7) << 4)));
        s[f] = __builtin_amdgcn_mfma_f32_16x16x32_bf16(q[ks].b, kb.b, s[f], 0, 0, 0);
      }
    }
    __builtin_amdgcn_s_setprio(0);

    // ---- online softmax; lane's rows = (l>>4)*4+i ----
    float mt[4];
#pragma unroll
    for (int i = 0; i < 4; ++i)
      mt[i] = fmaxf(fmaxf(s[0][i], s[1][i]), fmaxf(s[2][i], s[3][i]));
#pragma unroll
    for (int mask = 1; mask <= 8; mask <<= 1)
#pragma unroll
      for (int i = 0; i < 4; ++i) mt[i] = fmaxf(mt[i], __shfl_xor(mt[i], mask, 64));

    float al[4];
#pragma unroll
    for (int i = 0; i < 4; ++i) {
      float mn = fmaxf(m_run[i], mt[i]);
      al[i] = __expf(m_run[i] - mn);
      m_run[i] = mn;
    }
    float ps[4] = {0.f, 0.f, 0.f, 0.f};
#pragma unroll
    for (int f = 0; f < 4; ++f)
#pragma unroll
      for (int i = 0; i < 4; ++i) {
        float p = __expf(s[f][i] - m_run[i]);
        ps[i] += p;
        Pw[((lane >> 4) * 4 + i) * 68 + f * 16 + (lane & 15)] = f2b(p);
      }
#pragma unroll
    for (int mask = 1; mask <= 8; mask <<= 1)
#pragma unroll
      for (int i = 0; i < 4; ++i) ps[i] += __shfl_xor(ps[i], mask, 64);
#pragma unroll
    for (int i = 0; i < 4; ++i) l_run[i] = l_run[i] * al[i] + ps[i];

    // ---- rescale O, then O += P*V (16 MFMA/wave) ----
#pragma unroll
    for (int f = 0; f < 8; ++f)
#pragma unroll
      for (int i = 0; i < 4; ++i) o[f][i] *= al[i];

    B8 pa[2];
#pragma unroll
    for (int k2 = 0; k2 < 2; ++k2) {
      const u16* pp = Pw + (lane & 15) * 68 + k2 * 32 + (lane >> 4) * 8;
      pa[k2].d[0] = *(const uint2*)(pp);
      pa[k2].d[1] = *(const uint2*)(pp + 4);
    }
    __builtin_amdgcn_s_setprio(1);
#pragma unroll
    for (int f = 0; f < 8; ++f) {
      int r = f * 16 + (lane & 15);
#pragma unroll
      for (int k2 = 0; k2 < 2; ++k2) {
        int lb = r * 128 + k2 * 64 + (lane >> 4) * 16;
        B8 vb;
        vb.u = *(const uint4*)((const char*)Vs[cur] + (lb ^ ((r & 7) << 4)));
        o[f] = __builtin_amdgcn_mfma_f32_16x16x32_bf16(pa[k2].b, vb.b, o[f], 0, 0, 0);
      }
    }
    __builtin_amdgcn_s_setprio(0);

    __syncthreads();  // drains stage vmcnt; next tile ready, cur buffer reusable
  }

  // normalize and write R in (t, n*128+h) layout
#pragma unroll
  for (int i = 0; i < 4; ++i) {
    float inv = 1.0f / l_run[i];
    int row = q0 + w * 16 + (lane >> 4) * 4 + i;
#pragma unroll
    for (int f = 0; f < 8; ++f) {
      int col = head * 128 + f * 16 + (lane & 15);
      Rb[(size_t)row * 2048 + col] = f2b(o[f][i] * inv);
    }
  }
}

// ---------------- output projection: out = R(2048x2048) * W_out (dbuf) ----------------
__global__ __launch_bounds__(256) void out_gemm_kernel(const u16* __restrict__ Rb,
                                                       const u16* __restrict__ Wob,
                                                       float* __restrict__ out) {
  __shared__ __align__(16) u16 As[2][128 * 64];
  __shared__ __align__(16) u16 Bs[2][128 * 64];
  int tid = threadIdx.x;
  int o = blockIdx.x;
  int swz = (o & 7) * 32 + (o >> 3);
  int m0 = (swz & 15) * 128, n0 = (swz >> 4) * 128;
  f32x4 z = {0.f, 0.f, 0.f, 0.f};
  f32x4 acc[4][4];
#pragma unroll
  for (int i = 0; i < 4; ++i)
#pragma unroll
    for (int j = 0; j < 4; ++j) acc[i][j] = z;
  gemm_mainloop_dbuf(Rb + (size_t)m0 * 2048, Wob + (size_t)n0 * 2048,
                     As[0], Bs[0], As[1], Bs[1], acc, tid);

  int lane = tid & 63, wr = tid >> 7, wc = (tid >> 6) & 1;
#pragma unroll
  for (int i = 0; i < 4; ++i) {
    int rb = m0 + wr * 64 + i * 16 + (lane >> 4) * 4;
#pragma unroll
    for (int j = 0; j < 4; ++j) {
      int col = n0 + wc * 64 + j * 16 + (lane & 15);
#pragma unroll
      for (int r = 0; r < 4; ++r)
        out[(size_t)(rb + r) * 2048 + col] = acc[i][j][r];
    }
  }
}

extern "C" void kernel_launch(void* const* d_in, const int* in_sizes, int n_in,
                              void* d_out, int out_size, void* d_ws, size_t ws_size,
                              hipStream_t stream) {
  const float* X  = (const float*)d_in[0];
  const float* WQ = (const float*)d_in[1];
  const float* WK = (const float*)d_in[2];
  const float* WV = (const float*)d_in[3];
  const float* WO = (const float*)d_in[4];
  float* out = (float*)d_out;

  char* ws = (char*)d_ws;
  const size_t MB8 = 8u << 20;
  u16* Xb    = (u16*)(ws);
  u16* Wqkvb = (u16*)(ws + MB8);          // 3 x 8 MiB
  u16* Woutb = (u16*)(ws + 4 * MB8);
  u16* Qb    = (u16*)(ws + 5 * MB8);
  u16* Kb    = (u16*)(ws + 6 * MB8);
  u16* VTb   = (u16*)(ws + 7 * MB8);
  u16* Rbuf  = (u16*)(ws + MB8);          // aliases Wqkvb[W_Q]: dead after qkv_gemm

  prep_kernel<<<dim3(20480), dim3(256), 0, stream>>>(X, WQ, WK, WV, WO, Xb, Wqkvb, Woutb);
  qkv_gemm_kernel<<<dim3(768), dim3(256), 0, stream>>>(Xb, Wqkvb, Qb, Kb, VTb);
  attn_kernel<<<dim3(512), dim3(256), 0, stream>>>(Qb, Kb, VTb, Rbuf);
  out_gemm_kernel<<<dim3(256), dim3(256), 0, stream>>>(Rbuf, Woutb, out);
}

// Round 8
// 300.259 us; speedup vs baseline: 1.5703x; 1.0521x over previous
//
#include <hip/hip_runtime.h>

// MHSA: X(1,2048,2048) fp32; W_Q/K/V(16,2048,128); W_out(2048,2048); out (2048,2048) fp32.
// R8: attn softmax path rewritten with swapped-operand QK^T (S^T = mfma(K,Q)) so each lane
// owns ONE q-row and 16 kv-scores in-register: row reduce = 15 in-lane ops + 2 shuffles
// (was 32 shuffles); P never touches LDS (cvt_pk bf16 pack + 16 shfl redistribution to PV
// B-frags; was 16 ds_write_b16 + 4 ds_read_b64 -> the 4.2M bank conflicts); PV computes
// O^T = mfma(V^T, P); defer-max (T13, THR=8) skips O-rescale most iters. K/V staging,
// swizzles, and fragment LDS reads byte-identical to R7. Ps LDS freed (74->64 KB).
// Workspace layout (needs 64 MiB): see round 0 comment (unchanged).

typedef unsigned short u16;
typedef __bf16 bf16x8 __attribute__((ext_vector_type(8)));
typedef float f32x4 __attribute__((ext_vector_type(4)));
typedef __attribute__((address_space(1))) void gvoid;
typedef __attribute__((address_space(3))) void svoid;

union B8 { uint4 u; uint2 d[2]; unsigned int w[4]; bf16x8 b; };

__device__ __forceinline__ u16 f2b(float f) {
  unsigned int u = __float_as_uint(f);
  unsigned int r = (u + 0x7FFFu + ((u >> 16) & 1u)) >> 16;  // RNE
  return (u16)r;
}

// ---------------- fused prep: cvt X + transpose-cvt all W ----------------
__global__ __launch_bounds__(256) void prep_kernel(const float* __restrict__ X,
                                                   const float* __restrict__ WQ,
                                                   const float* __restrict__ WK,
                                                   const float* __restrict__ WV,
                                                   const float* __restrict__ WO,
                                                   u16* __restrict__ Xb,
                                                   u16* __restrict__ Wqkvb,
                                                   u16* __restrict__ Woutb) {
  int bid = blockIdx.x;
  int seg = bid >> 12;       // 0..4
  int sub = bid & 4095;
  int tid = threadIdx.x;
  if (seg == 0) {            // cvt_x: 4096 blocks * 1024 elems
    int i = (sub * 256 + tid) * 4;
    float4 v = *(const float4*)(X + i);
    ushort4 o;
    o.x = f2b(v.x); o.y = f2b(v.y); o.z = f2b(v.z); o.w = f2b(v.w);
    *(ushort4*)(Xb + i) = o;
    return;
  }
  __shared__ float t[32][33];
  const float* S;
  u16* D;
  int N, n0, k0;
  if (seg <= 3) {            // W_Q/K/V: per head K=2048 x N=128 -> (head, 128, 2048)
    const float* W = (seg == 1) ? WQ : (seg == 2) ? WK : WV;
    int head = sub >> 8, rest = sub & 255;
    N = 128;
    S = W + (size_t)head * 2048 * 128;
    D = Wqkvb + (size_t)(seg - 1) * 16 * 2048 * 128 + (size_t)head * 2048 * 128;
    n0 = (rest & 3) * 32;
    k0 = (rest >> 2) * 32;
  } else {                   // W_out: 2048x2048 transposed
    N = 2048;
    S = WO;
    D = Woutb;
    n0 = (sub & 63) * 32;
    k0 = (sub >> 6) * 32;
  }
  int tx = tid & 31, ty = tid >> 5;  // (32,8)
#pragma unroll
  for (int d = 0; d < 4; ++d)
    t[ty + d * 8][tx] = S[(size_t)(k0 + ty + d * 8) * N + n0 + tx];
  __syncthreads();
#pragma unroll
  for (int d = 0; d < 4; ++d)
    D[(size_t)(n0 + ty + d * 8) * 2048 + k0 + tx] = f2b(t[tx][ty + d * 8]);
}

// ---------------- GEMM building blocks: 128x128 tile, BK=64 --------------------
__device__ __forceinline__ void stage_tile(const u16* Ag, const u16* Bg,
                                           u16* As, u16* Bs, int k0, int tid) {
#pragma unroll
  for (int it = 0; it < 4; ++it) {
    int s = it * 256 + tid;
    int pb = s * 16;                           // physical (linear) LDS byte
    int lb = pb ^ ((((pb) >> 7) & 7) << 4);    // logical byte (involution)
    int row = lb >> 7;                         // 0..127
    int k8 = (lb >> 4) & 7;                    // 16B granule within row
    const u16* ga = Ag + (size_t)row * 2048 + k0 + k8 * 8;
    const u16* gb = Bg + (size_t)row * 2048 + k0 + k8 * 8;
    char* la = (char*)As + it * 4096 + (tid & 192) * 16;  // wave-uniform base
    char* lb2 = (char*)Bs + it * 4096 + (tid & 192) * 16;
    __builtin_amdgcn_global_load_lds((gvoid*)(void*)ga, (svoid*)la, 16, 0, 0);
    __builtin_amdgcn_global_load_lds((gvoid*)(void*)gb, (svoid*)lb2, 16, 0, 0);
  }
}

__device__ __forceinline__ void compute_tile(const u16* As, const u16* Bs,
                                             f32x4 acc[4][4], int lane, int wr, int wc) {
#pragma unroll
  for (int ks = 0; ks < 2; ++ks) {
    B8 a[4], b[4];
#pragma unroll
    for (int i = 0; i < 4; ++i) {
      int rowa = wr * 64 + i * 16 + (lane & 15);
      int ba = rowa * 128 + ks * 64 + (lane >> 4) * 16;
      ba ^= (rowa & 7) << 4;
      a[i].u = *(const uint4*)((const char*)As + ba);
      int rowb = wc * 64 + i * 16 + (lane & 15);
      int bb = rowb * 128 + ks * 64 + (lane >> 4) * 16;
      bb ^= (rowb & 7) << 4;
      b[i].u = *(const uint4*)((const char*)Bs + bb);
    }
    __builtin_amdgcn_s_setprio(1);
#pragma unroll
    for (int i = 0; i < 4; ++i)
#pragma unroll
      for (int j = 0; j < 4; ++j)
        acc[i][j] = __builtin_amdgcn_mfma_f32_16x16x32_bf16(a[i].b, b[j].b, acc[i][j], 0, 0, 0);
    __builtin_amdgcn_s_setprio(0);
  }
}

__device__ __forceinline__ void gemm_mainloop(const u16* Ag, const u16* Bg,
                                              u16* As, u16* Bs,
                                              f32x4 acc[4][4], int tid) {
  const int lane = tid & 63;
  const int wr = tid >> 7, wc = (tid >> 6) & 1;  // 4 waves in 2x2, wave tile 64x64
  for (int k0 = 0; k0 < 2048; k0 += 64) {
    __syncthreads();
    stage_tile(Ag, Bg, As, Bs, k0, tid);
    __syncthreads();
    compute_tile(As, Bs, acc, lane, wr, wc);
  }
}

__device__ __forceinline__ void gemm_mainloop_dbuf(const u16* Ag, const u16* Bg,
                                                   u16* As0, u16* Bs0, u16* As1, u16* Bs1,
                                                   f32x4 acc[4][4], int tid) {
  const int lane = tid & 63;
  const int wr = tid >> 7, wc = (tid >> 6) & 1;
  stage_tile(Ag, Bg, As0, Bs0, 0, tid);
  __syncthreads();  // tile 0 ready
  for (int i = 0; i < 32; ++i) {
    u16* Ac = (i & 1) ? As1 : As0;
    u16* Bc = (i & 1) ? Bs1 : Bs0;
    u16* An = (i & 1) ? As0 : As1;
    u16* Bn = (i & 1) ? Bs0 : Bs1;
    if (i < 31) stage_tile(Ag, Bg, An, Bn, (i + 1) * 64, tid);  // async, in flight
    compute_tile(Ac, Bc, acc, lane, wr, wc);
    __syncthreads();
  }
}

// ---------------- fused QKV projection ----------------
__global__ __launch_bounds__(256) void qkv_gemm_kernel(const u16* __restrict__ Xb,
                                                       const u16* __restrict__ Wb,
                                                       u16* __restrict__ Qb,
                                                       u16* __restrict__ Kb,
                                                       u16* __restrict__ VTb) {
  __shared__ __align__(16) u16 As[128 * 64];
  __shared__ __align__(16) u16 Bs[128 * 64];
  int tid = threadIdx.x;
  int o = blockIdx.x;
  int swz = (o & 7) * 96 + (o >> 3);
  int m0 = (swz & 15) * 128;
  int c0 = swz >> 4;             // 0..47
  int tau = c0 >> 4, head = c0 & 15;
  f32x4 z = {0.f, 0.f, 0.f, 0.f};
  f32x4 acc[4][4];
#pragma unroll
  for (int i = 0; i < 4; ++i)
#pragma unroll
    for (int j = 0; j < 4; ++j) acc[i][j] = z;
  gemm_mainloop(Xb + (size_t)m0 * 2048, Wb + (size_t)c0 * 128 * 2048, As, Bs, acc, tid);

  int lane = tid & 63, wr = tid >> 7, wc = (tid >> 6) & 1;
  if (tau < 2) {
    u16* Oh = ((tau == 0) ? Qb : Kb) + (size_t)head * 2048 * 128;
    float sc = (tau == 0) ? 0.08838834764831845f : 1.0f;  // fold 1/sqrt(128) into Q
#pragma unroll
    for (int i = 0; i < 4; ++i) {
      int rb = m0 + wr * 64 + i * 16 + (lane >> 4) * 4;
#pragma unroll
      for (int j = 0; j < 4; ++j) {
        int col = wc * 64 + j * 16 + (lane & 15);
#pragma unroll
        for (int r = 0; r < 4; ++r)
          Oh[(size_t)(rb + r) * 128 + col] = f2b(acc[i][j][r] * sc);
      }
    }
  } else {  // V: store transposed (h, t)
    u16* Vh = VTb + (size_t)head * 128 * 2048;
#pragma unroll
    for (int i = 0; i < 4; ++i) {
      int rb = m0 + wr * 64 + i * 16 + (lane >> 4) * 4;
#pragma unroll
      for (int j = 0; j < 4; ++j) {
        int col = wc * 64 + j * 16 + (lane & 15);
        ushort4 v;
        v.x = f2b(acc[i][j][0]); v.y = f2b(acc[i][j][1]);
        v.z = f2b(acc[i][j][2]); v.w = f2b(acc[i][j][3]);
        *(ushort4*)(Vh + (size_t)col * 2048 + rb) = v;
      }
    }
  }
}

// ---------------- flash attention (swapped QK^T, in-register softmax) ----------------
// 1D grid 512; swz: XCD x owns heads {2x,2x+1} -> KV (2MB) L2-resident.
// 4 waves x 16 q-rows, KV tile 64; dbuf global_load_lds staging (as R6/R7).
// S^T = mfma(K,Q): lane (g=l>>4, q=l&15) holds S[kv=f*16+g*4+i][q] -> softmax reduce is
// 15 in-lane ops + 2 shfl. P packed to bf16 (cvt_pk) + redistributed via 16 shfl into
// PV B-frags (kv=k2*32+g*8+e per lane). O^T = mfma(V^T, P): o[f][r]=O[q][d=f*16+g*4+r].
__global__ __launch_bounds__(256, 2) void attn_kernel(const u16* __restrict__ Qb,
                                                      const u16* __restrict__ Kb,
                                                      const u16* __restrict__ VTb,
                                                      u16* __restrict__ Rb) {
  __shared__ __align__(16) u16 Ks[2][64 * 128];
  __shared__ __align__(16) u16 Vs[2][128 * 64];
  int tid = threadIdx.x, lane = tid & 63, w = tid >> 6;
  int bid = blockIdx.x;
  int swz = (bid & 7) * 64 + (bid >> 3);
  int head = swz >> 5;
  int q0 = (swz & 31) * 64;
  const u16* Qh = Qb + (size_t)head * 2048 * 128;
  const u16* Kh = Kb + (size_t)head * 2048 * 128;
  const u16* Vh = VTb + (size_t)head * 128 * 2048;
  const int g = lane >> 4;

  // Q fragments (B-operand now; same layout: row=q=l&15, k=(l>>4)*8.. contig)
  B8 q[4];
  {
    int qrow = q0 + w * 16 + (lane & 15);
#pragma unroll
    for (int ks = 0; ks < 4; ++ks)
      q[ks].u = *(const uint4*)(Qh + (size_t)qrow * 128 + ks * 32 + (lane >> 4) * 8);
  }

  f32x4 o[8];   // o[f][r] = O[q=l&15 (+w*16+q0)][d = f*16 + g*4 + r]
  f32x4 z4 = {0.f, 0.f, 0.f, 0.f};
#pragma unroll
  for (int f = 0; f < 8; ++f) o[f] = z4;
  float m_run = -1e30f, l_run = 0.f;

  auto STAGE = [&](int bi, int s0) {
#pragma unroll
    for (int it2 = 0; it2 < 4; ++it2) {
      int pb = (it2 * 256 + tid) * 16;
      int lbK = pb ^ (((pb >> 8) & 7) << 4);
      int rowK = lbK >> 8;
      int k8 = (lbK >> 4) & 15;
      const u16* gk = Kh + (size_t)(s0 + rowK) * 128 + k8 * 8;
      char* dk = (char*)Ks[bi] + it2 * 4096 + (tid & 192) * 16;
      __builtin_amdgcn_global_load_lds((gvoid*)(void*)gk, (svoid*)dk, 16, 0, 0);
      int lbV = pb ^ (((pb >> 7) & 7) << 4);
      int rowV = lbV >> 7;
      int t8 = (lbV >> 4) & 7;
      const u16* gv = Vh + (size_t)rowV * 2048 + s0 + t8 * 8;
      char* dv = (char*)Vs[bi] + it2 * 4096 + (tid & 192) * 16;
      __builtin_amdgcn_global_load_lds((gvoid*)(void*)gv, (svoid*)dv, 16, 0, 0);
    }
  };

  STAGE(0, 0);
  __syncthreads();

  for (int it = 0; it < 32; ++it) {
    int cur = it & 1;
    if (it < 31) STAGE(cur ^ 1, (it + 1) * 64);

    // ---- S^T = K Q^T: s[f][i] = S[kv=f*16+g*4+i][q] ----
    f32x4 s[4];
#pragma unroll
    for (int f = 0; f < 4; ++f) s[f] = z4;
    __builtin_amdgcn_s_setprio(1);
#pragma unroll
    for (int f = 0; f < 4; ++f) {
      int r = f * 16 + (lane & 15);
#pragma unroll
      for (int ks = 0; ks < 4; ++ks) {
        int lb = r * 256 + ks * 64 + (lane >> 4) * 16;
        B8 kb;
        kb.u = *(const uint4*)((const char*)Ks[cur] + (lb ^ ((r & 7) << 4)));
        s[f] = __builtin_amdgcn_mfma_f32_16x16x32_bf16(kb.b, q[ks].b, s[f], 0, 0, 0);
      }
    }
    __builtin_amdgcn_s_setprio(0);

    // ---- in-register softmax (one q-row per lane) ----
    float mt = s[0][0];
#pragma unroll
    for (int f = 0; f < 4; ++f)
#pragma unroll
      for (int i = 0; i < 4; ++i) mt = fmaxf(mt, s[f][i]);
    mt = fmaxf(mt, __shfl_xor(mt, 16, 64));
    mt = fmaxf(mt, __shfl_xor(mt, 32, 64));

    if (!__all(mt - m_run <= 8.0f)) {   // defer-max (T13): rescale only on real growth
      float mn = fmaxf(m_run, mt);
      float al = __expf(m_run - mn);
      m_run = mn;
      l_run *= al;
#pragma unroll
      for (int f = 0; f < 8; ++f)
#pragma unroll
        for (int r = 0; r < 4; ++r) o[f][r] *= al;
    }
    float ps = 0.f;
#pragma unroll
    for (int f = 0; f < 4; ++f)
#pragma unroll
      for (int i = 0; i < 4; ++i) {
        float p = __expf(s[f][i] - m_run);
        ps += p;
        s[f][i] = p;
      }
    ps += __shfl_xor(ps, 16, 64);
    ps += __shfl_xor(ps, 32, 64);
    l_run += ps;

    // ---- pack P to bf16 pairs: cl[f]=(kv f*16+4g, +1), ch[f]=(+2, +3) ----
    unsigned int cl[4], ch[4];
#pragma unroll
    for (int f = 0; f < 4; ++f) {
      asm("v_cvt_pk_bf16_f32 %0, %1, %2" : "=v"(cl[f]) : "v"(s[f][0]), "v"(s[f][1]));
      asm("v_cvt_pk_bf16_f32 %0, %1, %2" : "=v"(ch[f]) : "v"(s[f][2]), "v"(s[f][3]));
    }
    // ---- redistribute to PV B-frags: lane needs kv = k2*32 + g*8 + e (e=0..7),
    // sourced from lane groups 2(g&1), 2(g&1)+1 at frag f = 2k2 + (g>>1) ----
    int srcA = ((g & 1) << 5) | (lane & 15);
    int srcB = srcA + 16;
    int hi = g >> 1;
    B8 pa0, pa1;
    {
      unsigned int a0 = __shfl((int)cl[0], srcA, 64), b0 = __shfl((int)cl[1], srcA, 64);
      unsigned int a1 = __shfl((int)ch[0], srcA, 64), b1 = __shfl((int)ch[1], srcA, 64);
      unsigned int a2 = __shfl((int)cl[0], srcB, 64), b2 = __shfl((int)cl[1], srcB, 64);
      unsigned int a3 = __shfl((int)ch[0], srcB, 64), b3 = __shfl((int)ch[1], srcB, 64);
      pa0.w[0] = hi ? b0 : a0; pa0.w[1] = hi ? b1 : a1;
      pa0.w[2] = hi ? b2 : a2; pa0.w[3] = hi ? b3 : a3;
      unsigned int c0 = __shfl((int)cl[2], srcA, 64), d0 = __shfl((int)cl[3], srcA, 64);
      unsigned int c1 = __shfl((int)ch[2], srcA, 64), d1 = __shfl((int)ch[3], srcA, 64);
      unsigned int c2 = __shfl((int)cl[2], srcB, 64), d2 = __shfl((int)cl[3], srcB, 64);
      unsigned int c3 = __shfl((int)ch[2], srcB, 64), d3 = __shfl((int)ch[3], srcB, 64);
      pa1.w[0] = hi ? d0 : c0; pa1.w[1] = hi ? d1 : c1;
      pa1.w[2] = hi ? d2 : c2; pa1.w[3] = hi ? d3 : c3;
    }

    // ---- O^T += V^T P: A=V^T (row=d=l&15, k=kv), B=pa ----
    __builtin_amdgcn_s_setprio(1);
#pragma unroll
    for (int f = 0; f < 8; ++f) {
      int r = f * 16 + (lane & 15);
      {
        int lb = r * 128 + 0 * 64 + (lane >> 4) * 16;
        B8 vb;
        vb.u = *(const uint4*)((const char*)Vs[cur] + (lb ^ ((r & 7) << 4)));
        o[f] = __builtin_amdgcn_mfma_f32_16x16x32_bf16(vb.b, pa0.b, o[f], 0, 0, 0);
      }
      {
        int lb = r * 128 + 1 * 64 + (lane >> 4) * 16;
        B8 vb;
        vb.u = *(const uint4*)((const char*)Vs[cur] + (lb ^ ((r & 7) << 4)));
        o[f] = __builtin_amdgcn_mfma_f32_16x16x32_bf16(vb.b, pa1.b, o[f], 0, 0, 0);
      }
    }
    __builtin_amdgcn_s_setprio(0);

    __syncthreads();  // drains stage vmcnt; next tile ready, cur buffer reusable
  }

  // normalize and write R in (t, n*128+h) layout; 4 consecutive d per frag -> ushort4
  float inv = 1.0f / l_run;
  int row = q0 + w * 16 + (lane & 15);
#pragma unroll
  for (int f = 0; f < 8; ++f) {
    ushort4 v;
    v.x = f2b(o[f][0] * inv); v.y = f2b(o[f][1] * inv);
    v.z = f2b(o[f][2] * inv); v.w = f2b(o[f][3] * inv);
    *(ushort4*)(Rb + (size_t)row * 2048 + head * 128 + f * 16 + g * 4) = v;
  }
}

// ---------------- output projection: out = R(2048x2048) * W_out (dbuf) ----------------
__global__ __launch_bounds__(256) void out_gemm_kernel(const u16* __restrict__ Rb,
                                                       const u16* __restrict__ Wob,
                                                       float* __restrict__ out) {
  __shared__ __align__(16) u16 As[2][128 * 64];
  __shared__ __align__(16) u16 Bs[2][128 * 64];
  int tid = threadIdx.x;
  int o = blockIdx.x;
  int swz = (o & 7) * 32 + (o >> 3);
  int m0 = (swz & 15) * 128, n0 = (swz >> 4) * 128;
  f32x4 z = {0.f, 0.f, 0.f, 0.f};
  f32x4 acc[4][4];
#pragma unroll
  for (int i = 0; i < 4; ++i)
#pragma unroll
    for (int j = 0; j < 4; ++j) acc[i][j] = z;
  gemm_mainloop_dbuf(Rb + (size_t)m0 * 2048, Wob + (size_t)n0 * 2048,
                     As[0], Bs[0], As[1], Bs[1], acc, tid);

  int lane = tid & 63, wr = tid >> 7, wc = (tid >> 6) & 1;
#pragma unroll
  for (int i = 0; i < 4; ++i) {
    int rb = m0 + wr * 64 + i * 16 + (lane >> 4) * 4;
#pragma unroll
    for (int j = 0; j < 4; ++j) {
      int col = n0 + wc * 64 + j * 16 + (lane & 15);
#pragma unroll
      for (int r = 0; r < 4; ++r)
        out[(size_t)(rb + r) * 2048 + col] = acc[i][j][r];
    }
  }
}

extern "C" void kernel_launch(void* const* d_in, const int* in_sizes, int n_in,
                              void* d_out, int out_size, void* d_ws, size_t ws_size,
                              hipStream_t stream) {
  const float* X  = (const float*)d_in[0];
  const float* WQ = (const float*)d_in[1];
  const float* WK = (const float*)d_in[2];
  const float* WV = (const float*)d_in[3];
  const float* WO = (const float*)d_in[4];
  float* out = (float*)d_out;

  char* ws = (char*)d_ws;
  const size_t MB8 = 8u << 20;
  u16* Xb    = (u16*)(ws);
  u16* Wqkvb = (u16*)(ws + MB8);          // 3 x 8 MiB
  u16* Woutb = (u16*)(ws + 4 * MB8);
  u16* Qb    = (u16*)(ws + 5 * MB8);
  u16* Kb    = (u16*)(ws + 6 * MB8);
  u16* VTb   = (u16*)(ws + 7 * MB8);
  u16* Rbuf  = (u16*)(ws + MB8);          // aliases Wqkvb[W_Q]: dead after qkv_gemm

  prep_kernel<<<dim3(20480), dim3(256), 0, stream>>>(X, WQ, WK, WV, WO, Xb, Wqkvb, Woutb);
  qkv_gemm_kernel<<<dim3(768), dim3(256), 0, stream>>>(Xb, Wqkvb, Qb, Kb, VTb);
  attn_kernel<<<dim3(512), dim3(256), 0, stream>>>(Qb, Kb, VTb, Rbuf);
  out_gemm_kernel<<<dim3(256), dim3(256), 0, stream>>>(Rbuf, Woutb, out);
}